// Round 7
// baseline (1191.173 us; speedup 1.0000x reference)
//
#include <hip/hip_runtime.h>

#define PLANE 4096
#define OFF_ELEMS 294912
#define CLS_OFF   589824

typedef __attribute__((ext_vector_type(4))) float f32x4;
typedef __attribute__((ext_vector_type(8))) short bf16x8;

__device__ __forceinline__ float bf2f(ushort u) {
  union { uint u; float f; } x; x.u = ((uint)u) << 16; return x.f;
}
__device__ __forceinline__ ushort f2bf(float f) {
  union { float f; uint u; } x; x.f = f;
  return (ushort)((x.u + 0x7fffu + ((x.u >> 16) & 1u)) >> 16);
}
__device__ __forceinline__ void gload_lds16(const void* g, void* l) {
  __builtin_amdgcn_global_load_lds(
      (const __attribute__((address_space(1))) void*)g,
      (__attribute__((address_space(3))) void*)l, 16, 0, 0);
}

// ---------------------------------------------------------------------------
// Row-pipelined NHWC bf16 MFMA conv3x3 (pad 1).  One block = one output row.
// Loop over the 3 input rows: stage row r+1 (32 KB, global_load_lds, granule
// XOR-swizzle) while computing row r's 3 kx-taps from LDS.  Double-buffered,
// one barrier per row.  LDS 64 KB -> 2 blocks/CU.  Weights tap-major
// [9][Cout][256] streamed from L2.  XCD-bijective grid swizzle.
// ---------------------------------------------------------------------------
template <int CO_TILE, bool OUT_BF16>
__global__ __launch_bounds__((CO_TILE == 256) ? 512 : 256, (CO_TILE == 256) ? 4 : 2)
void conv_std(const ushort* __restrict__ in, const ushort* __restrict__ wg,
              void* __restrict__ outp, int Cout) {
  constexpr int WAVES = (CO_TILE == 256) ? 8 : 4;
  constexpr int WM_WAVES = (CO_TILE == 256) ? 4 : 1;
  constexpr int WN_WAVES = WAVES / WM_WAVES;       // 2 or 4
  constexpr int WM_SUB = CO_TILE / WM_WAVES;       // 64 or 32
  constexpr int MFR = WM_SUB / 16;                 // 4 or 2
  constexpr int PX_SUB = 64 / WN_WAVES;            // 32 or 16
  constexpr int NFR = PX_SUB / 16;                 // 2 or 1
  constexpr int ISS = 32 / WAVES;                  // stage issues per wave

  __shared__ __align__(16) ushort Bs[2][16384];    // 2 x 32 KB row buffers

  const int bid = blockIdx.x;
  const int r8 = bid & 7;
  const int b = r8 >> 1;
  const int y = (r8 & 1) * 32 + (bid >> 3);
  const int t = threadIdx.x;
  const int wv = t >> 6, lane = t & 63, lm = lane & 15, kg = lane >> 4;
  const int wm = (WM_WAVES == 4) ? (wv & 3) : 0;
  const int wn = (WM_WAVES == 4) ? (wv >> 2) : wv;

  const ushort* inb = in + (size_t)b * (PLANE * 256);

  int rows[3], nr = 0;
#pragma unroll
  for (int r = 0; r < 3; ++r)
    if ((unsigned)(y + r - 1) < 64u) rows[nr++] = r;

  const int pxl = lane >> 5, gd = lane & 31;
  auto stage = [&](int r, int bufi) {
    const int iy = y + r - 1;
#pragma unroll
    for (int n = 0; n < ISS; ++n) {
      int i = wv * ISS + n;
      int px = i * 2 + pxl;
      int gs = gd ^ (px & 7);
      gload_lds16(inb + ((size_t)(iy * 64 + px)) * 256 + gs * 8,
                  (char*)Bs[bufi] + i * 1024);
    }
  };

  f32x4 acc[MFR][NFR] = {};
  const ushort* wrow[MFR];
#pragma unroll
  for (int mi = 0; mi < MFR; ++mi) {
    int cor = wm * WM_SUB + mi * 16 + lm;
    if (cor > Cout - 1) cor = Cout - 1;   // clamped rows go to D rows >= Cout (unstored)
    wrow[mi] = wg + (size_t)cor * 256 + kg * 8;
  }
  const int wks = Cout * 256;

  auto compute = [&](int r, int bufi) {
    const char* buf = (const char*)Bs[bufi];
#pragma unroll
    for (int kx = 0; kx < 3; ++kx) {
      const int kk = r * 3 + kx;
      int sb[NFR], swz[NFR];
      bool bval[NFR];
#pragma unroll
      for (int ni = 0; ni < NFR; ++ni) {
        int px = wn * PX_SUB + ni * 16 + lm;
        int ix = px + kx - 1;
        bval[ni] = (unsigned)ix < 64u;
        int ixc = min(max(ix, 0), 63);
        sb[ni] = ixc * 512;
        swz[ni] = ixc & 7;
      }
#pragma unroll
      for (int cc = 0; cc < 4; ++cc) {
        bf16x8 af[MFR][2], bf[NFR][2];
#pragma unroll
        for (int mi = 0; mi < MFR; ++mi)
#pragma unroll
          for (int ks = 0; ks < 2; ++ks)
            af[mi][ks] = *(const bf16x8*)(wrow[mi] + kk * wks + cc * 64 + ks * 32);
        bf16x8 z = {};
#pragma unroll
        for (int ni = 0; ni < NFR; ++ni)
#pragma unroll
          for (int ks = 0; ks < 2; ++ks) {
            int g = (cc * 8 + ks * 4 + kg) ^ swz[ni];
            bf16x8 v = *(const bf16x8*)(buf + sb[ni] + g * 16);
            bf[ni][ks] = bval[ni] ? v : z;
          }
        __builtin_amdgcn_s_setprio(1);
#pragma unroll
        for (int mi = 0; mi < MFR; ++mi)
#pragma unroll
          for (int ni = 0; ni < NFR; ++ni)
#pragma unroll
            for (int ks = 0; ks < 2; ++ks)
              acc[mi][ni] = __builtin_amdgcn_mfma_f32_16x16x32_bf16(
                  af[mi][ks], bf[ni][ks], acc[mi][ni], 0, 0, 0);
        __builtin_amdgcn_s_setprio(0);
      }
    }
  };

  stage(rows[0], 0);
  asm volatile("s_waitcnt vmcnt(0)" ::: "memory");
  __syncthreads();
  for (int i = 0; i < nr; ++i) {
    if (i + 1 < nr) stage(rows[i + 1], (i + 1) & 1);
    compute(rows[i], i & 1);
    asm volatile("s_waitcnt vmcnt(0)" ::: "memory");
    __syncthreads();
  }

  // ---- epilogue ----
  if (OUT_BF16) {
    ushort* outb = (ushort*)outp + (size_t)b * (PLANE * 256) + (size_t)y * 64 * 256;
#pragma unroll
    for (int mi = 0; mi < MFR; ++mi)
#pragma unroll
      for (int ni = 0; ni < NFR; ++ni) {
        int px = wn * PX_SUB + ni * 16 + lm;
        int co0 = wm * WM_SUB + mi * 16 + kg * 4;
        ushort4 h;
        h.x = f2bf(acc[mi][ni][0]); h.y = f2bf(acc[mi][ni][1]);
        h.z = f2bf(acc[mi][ni][2]); h.w = f2bf(acc[mi][ni][3]);
        *(ushort4*)(outb + (size_t)px * 256 + co0) = h;
      }
  } else {
    float* o = (float*)outp;
#pragma unroll
    for (int mi = 0; mi < MFR; ++mi)
#pragma unroll
      for (int ni = 0; ni < NFR; ++ni) {
        int px = wn * PX_SUB + ni * 16 + lm;
#pragma unroll
        for (int rr = 0; rr < 4; ++rr) {
          int co = wm * WM_SUB + mi * 16 + kg * 4 + rr;
          if (co < Cout)
            o[((size_t)(b * Cout + co)) * PLANE + y * 64 + px] = acc[mi][ni][rr];
        }
      }
  }
}

// ---------------------------------------------------------------------------
// Tap-pipelined deformable conv3x3 (v1).  One blended tap-plane (32 KB)
// double-buffered: per tap, issue next tap's 16 bilinear gathers (2 batches
// of 8), compute current tap's MFMA, blend+ds_write, one barrier per tap.
// ---------------------------------------------------------------------------
__global__ __launch_bounds__(512, 4) void conv_dfm(
    const ushort* __restrict__ in, const ushort* __restrict__ wg,
    ushort* __restrict__ outp, const int4* __restrict__ idx4,
    const float4* __restrict__ wt4) {
  __shared__ __align__(16) ushort Ds[2][16384];

  const int bid = blockIdx.x;
  const int r8 = bid & 7;
  const int b = r8 >> 1;
  const int y = (r8 & 1) * 32 + (bid >> 3);
  const int t = threadIdx.x;
  const int wv = t >> 6, lane = t & 63, lm = lane & 15, kg = lane >> 4;
  const int wm = wv & 3, wn = wv >> 2;
  const int spx = t >> 3, gd = t & 7;      // stage: pixel / low-granule

  const ushort* inb = in + (size_t)b * (PLANE * 256);

  int4 tA; float4 wA;                       // table for the tap being gathered
  auto ldtbl = [&](int kk) {
    int pi = ((b * 9 + kk) * 64 + y) * 64 + spx;
    tA = idx4[pi]; wA = wt4[pi];
  };

  bf16x8 g[8];                              // 8 in-flight gathers (2 cc chunks)
  auto gather = [&](int ccp) {
#pragma unroll
    for (int q = 0; q < 2; ++q) {
      int cc = ccp * 2 + q;
      const ushort* cb = inb + (cc * 8 + gd) * 8;
      g[q * 4 + 0] = *(const bf16x8*)(cb + (size_t)tA.x * 256);
      g[q * 4 + 1] = *(const bf16x8*)(cb + (size_t)tA.y * 256);
      g[q * 4 + 2] = *(const bf16x8*)(cb + (size_t)tA.z * 256);
      g[q * 4 + 3] = *(const bf16x8*)(cb + (size_t)tA.w * 256);
    }
  };
  auto blend = [&](int ccp, int nb) {
#pragma unroll
    for (int q = 0; q < 2; ++q) {
      int cc = ccp * 2 + q;
      uint4 pk; ushort* hp = (ushort*)&pk;
#pragma unroll
      for (int j = 0; j < 8; ++j) {
        float f = wA.x * bf2f(((ushort*)&g[q * 4 + 0])[j])
                + wA.y * bf2f(((ushort*)&g[q * 4 + 1])[j])
                + wA.z * bf2f(((ushort*)&g[q * 4 + 2])[j])
                + wA.w * bf2f(((ushort*)&g[q * 4 + 3])[j]);
        hp[j] = f2bf(f);
      }
      int slot = (cc * 8 + gd) ^ (spx & 7);
      *(uint4*)((char*)Ds[nb] + spx * 512 + slot * 16) = pk;
    }
  };

  f32x4 acc[4][2] = {};
  const ushort* wrow[4];
#pragma unroll
  for (int mi = 0; mi < 4; ++mi)
    wrow[mi] = wg + (size_t)(wm * 64 + mi * 16 + lm) * 256 + kg * 8;

  int pxn[2], swz[2];
#pragma unroll
  for (int ni = 0; ni < 2; ++ni) {
    pxn[ni] = (wn * 32 + ni * 16 + lm) * 512;
    swz[ni] = (wn * 32 + ni * 16 + lm) & 7;
  }

  auto compute_cc = [&](int kk, int cur, int cc) {
    bf16x8 af[4][2], bf[2][2];
#pragma unroll
    for (int mi = 0; mi < 4; ++mi)
#pragma unroll
      for (int ks = 0; ks < 2; ++ks)
        af[mi][ks] = *(const bf16x8*)(wrow[mi] + kk * 65536 + cc * 64 + ks * 32);
#pragma unroll
    for (int ni = 0; ni < 2; ++ni)
#pragma unroll
      for (int ks = 0; ks < 2; ++ks) {
        int gs = (cc * 8 + ks * 4 + kg) ^ swz[ni];
        bf[ni][ks] = *(const bf16x8*)((const char*)Ds[cur] + pxn[ni] + gs * 16);
      }
    __builtin_amdgcn_s_setprio(1);
#pragma unroll
    for (int mi = 0; mi < 4; ++mi)
#pragma unroll
      for (int ni = 0; ni < 2; ++ni)
#pragma unroll
        for (int ks = 0; ks < 2; ++ks)
          acc[mi][ni] = __builtin_amdgcn_mfma_f32_16x16x32_bf16(
              af[mi][ks], bf[ni][ks], acc[mi][ni], 0, 0, 0);
    __builtin_amdgcn_s_setprio(0);
  };

  // prologue: blend tap 0 into Ds[0]
  ldtbl(0);
  gather(0); blend(0, 0);
  gather(1); blend(1, 0);
  ldtbl(1);
  __syncthreads();

  for (int kk = 0; kk < 9; ++kk) {
    const int cur = kk & 1, nb = cur ^ 1;
    const bool pf = (kk < 8);
    if (pf) gather(0);                 // tap kk+1, cc 0-1 (uses tA = tbl kk+1)
    compute_cc(kk, cur, 0);
    compute_cc(kk, cur, 1);
    if (pf) { blend(0, nb); gather(1); }
    compute_cc(kk, cur, 2);
    compute_cc(kk, cur, 3);
    if (pf) {
      blend(1, nb);
      if (kk + 2 < 9) ldtbl(kk + 2);
    }
    __syncthreads();
  }

  ushort* outb = outp + (size_t)b * (PLANE * 256) + (size_t)y * 64 * 256;
#pragma unroll
  for (int mi = 0; mi < 4; ++mi)
#pragma unroll
    for (int ni = 0; ni < 2; ++ni) {
      int px = wn * 32 + ni * 16 + lm;
      int co0 = wm * 64 + mi * 16 + kg * 4;
      ushort4 h;
      h.x = f2bf(acc[mi][ni][0]); h.y = f2bf(acc[mi][ni][1]);
      h.z = f2bf(acc[mi][ni][2]); h.w = f2bf(acc[mi][ni][3]);
      *(ushort4*)(outb + (size_t)px * 256 + co0) = h;
    }
}

// ---------------------------------------------------------------------------
// fp32 NCHW feature -> bf16 NHWC
// ---------------------------------------------------------------------------
__global__ __launch_bounds__(256) void tr_nhwc(const float* __restrict__ src,
                                               ushort* __restrict__ dst) {
  __shared__ ushort T[64][264];
  int y = blockIdx.x, b = blockIdx.y, t = threadIdx.x;
  const float* s = src + (size_t)b * 1048576 + y * 64;
  int ci0 = t >> 2, f4 = t & 3;
#pragma unroll
  for (int cb = 0; cb < 4; ++cb) {
    int ci = cb * 64 + ci0;
#pragma unroll
    for (int l = 0; l < 4; ++l) {
      int px = (f4 + l * 4) * 4;
      float4 v = *(const float4*)(s + (size_t)ci * 4096 + px);
      T[px + 0][ci] = f2bf(v.x);
      T[px + 1][ci] = f2bf(v.y);
      T[px + 2][ci] = f2bf(v.z);
      T[px + 3][ci] = f2bf(v.w);
    }
  }
  __syncthreads();
  ushort* d = dst + (size_t)(b * 4096 + y * 64) * 256;
#pragma unroll
  for (int k = 0; k < 8; ++k) {
    int u = t + k * 256;
    int px = u >> 5, c32 = u & 31;
    uint4 vv = *(const uint4*)&T[px][c32 * 8];
    *(uint4*)(d + (size_t)px * 256 + c32 * 8) = vv;
  }
}

// ---------------------------------------------------------------------------
__global__ __launch_bounds__(256) void precomp_offsets(
    const float* __restrict__ off, int4* __restrict__ idx4,
    float4* __restrict__ wt4) {
  int tid = blockIdx.x * 256 + threadIdx.x;
  if (tid >= 4 * 9 * PLANE) return;
  int x = tid & 63, y = (tid >> 6) & 63;
  int kk = (tid >> 12) % 9;
  int b = tid / (9 * PLANE);
  float dy = off[((b * 18 + 2 * kk) * 64 + y) * 64 + x];
  float dx = off[((b * 18 + 2 * kk + 1) * 64 + y) * 64 + x];
  float sy = dy + (float)(y - 1 + kk / 3);
  float sx = dx + (float)(x - 1 + kk % 3);
  float y0f = floorf(sy), x0f = floorf(sx);
  float wy = sy - y0f, wx = sx - x0f;
  int y0 = (int)y0f, x0 = (int)x0f, y1 = y0 + 1, x1 = x0 + 1;
  float vy0 = ((unsigned)y0 < 64u) ? 1.f : 0.f;
  float vy1 = ((unsigned)y1 < 64u) ? 1.f : 0.f;
  float vx0 = ((unsigned)x0 < 64u) ? 1.f : 0.f;
  float vx1 = ((unsigned)x1 < 64u) ? 1.f : 0.f;
  int cy0 = min(max(y0, 0), 63), cy1 = min(max(y1, 0), 63);
  int cx0 = min(max(x0, 0), 63), cx1 = min(max(x1, 0), 63);
  idx4[tid] = make_int4(cy0 * 64 + cx0, cy0 * 64 + cx1,
                        cy1 * 64 + cx0, cy1 * 64 + cx1);
  wt4[tid] = make_float4((1.f - wy) * (1.f - wx) * vy0 * vx0,
                         (1.f - wy) * wx * vy0 * vx1,
                         wy * (1.f - wx) * vy1 * vx0, wy * wx * vy1 * vx1);
}

// ---------------------------------------------------------------------------
__global__ __launch_bounds__(256) void gn_stats(const ushort* __restrict__ x,
                                                float2* __restrict__ stats) {
  int bg = blockIdx.x;
  int b = bg >> 5, g = bg & 31;
  const uint4* base = (const uint4*)(x + (size_t)b * 1048576 + g * 8);
  float s = 0.f, q = 0.f;
#pragma unroll
  for (int k = 0; k < 16; ++k) {
    int p = threadIdx.x + k * 256;
    uint4 v = base[(size_t)p * 32];
    const ushort* h = (const ushort*)&v;
#pragma unroll
    for (int j = 0; j < 8; ++j) { float f = bf2f(h[j]); s += f; q += f * f; }
  }
#pragma unroll
  for (int o = 32; o; o >>= 1) { s += __shfl_xor(s, o); q += __shfl_xor(q, o); }
  __shared__ float ss[4], qq[4];
  int wid = threadIdx.x >> 6;
  if ((threadIdx.x & 63) == 0) { ss[wid] = s; qq[wid] = q; }
  __syncthreads();
  if (threadIdx.x == 0) {
    s = ss[0] + ss[1] + ss[2] + ss[3];
    q = qq[0] + qq[1] + qq[2] + qq[3];
    float m = s / 32768.f;
    float v = q / 32768.f - m * m;
    stats[bg] = make_float2(m, rsqrtf(v + 1e-5f));
  }
}

__global__ __launch_bounds__(256) void gn_apply(
    const ushort* __restrict__ x, const float2* __restrict__ stats,
    const float* __restrict__ gamma, const float* __restrict__ beta,
    ushort* __restrict__ out) {
  int i = blockIdx.x * 256 + threadIdx.x;
  uint4 v = ((const uint4*)x)[i];
  int cg = i & 31;
  int b = i >> 17;
  float2 st = stats[b * 32 + cg];
  const float4* gp = (const float4*)(gamma + cg * 8);
  const float4* bp = (const float4*)(beta + cg * 8);
  float4 g0 = gp[0], g1 = gp[1], b0 = bp[0], b1 = bp[1];
  float ga[8] = {g0.x, g0.y, g0.z, g0.w, g1.x, g1.y, g1.z, g1.w};
  float bb[8] = {b0.x, b0.y, b0.z, b0.w, b1.x, b1.y, b1.z, b1.w};
  ushort* h = (ushort*)&v;
#pragma unroll
  for (int j = 0; j < 8; ++j) {
    float a = st.y * ga[j];
    h[j] = f2bf(bf2f(h[j]) * a + (bb[j] - st.x * a));
  }
  ((uint4*)out)[i] = v;
}

// ---------------------------------------------------------------------------
struct WJobs {
  const float* src[12];
  ushort* dst[12];
  int cout[12];
};
__global__ __launch_bounds__(256) void wcvt(WJobs j) {
  int job = blockIdx.z, kk = blockIdx.y, co = blockIdx.x, ci = threadIdx.x;
  int Cout = j.cout[job];
  if (co >= Cout) return;
  j.dst[job][((size_t)kk * Cout + co) * 256 + ci] =
      f2bf(j.src[job][co * 2304 + ci * 9 + kk]);
}

// ---------------------------------------------------------------------------
__global__ __launch_bounds__(256) void rp_out(const float* __restrict__ off1,
                                              const float* __restrict__ off2,
                                              float* __restrict__ out) {
  int tid = blockIdx.x * 256 + threadIdx.x;
  if (tid >= OFF_ELEMS) return;
  int x = tid & 63, y = (tid >> 6) & 63;
  int ch = (tid >> 12) % 18;
  int k = ch >> 1;
  float base = (ch & 1) ? (float)(x + (k % 3) - 1) : (float)(y + (k / 3) - 1);
  float r1 = base + off1[tid];
  out[tid] = r1;
  out[OFF_ELEMS + tid] = r1 + off2[tid];
}

// ---------------------------------------------------------------------------
extern "C" void kernel_launch(void* const* d_in, const int* in_sizes, int n_in,
                              void* d_out, int out_size, void* d_ws,
                              size_t ws_size, hipStream_t stream) {
  (void)in_sizes; (void)n_in; (void)out_size; (void)ws_size;
  const float* feature = (const float*)d_in[0];
  const float* loc_ws  = (const float*)d_in[1];
  const float* loc_g   = (const float*)d_in[2];
  const float* loc_b   = (const float*)d_in[3];
  const float* cls_ws  = (const float*)d_in[4];
  const float* cls_g   = (const float*)d_in[5];
  const float* cls_b   = (const float*)d_in[6];
  const float* pi_w    = (const float*)d_in[7];
  const float* pio_w   = (const float*)d_in[8];
  const float* prd_w   = (const float*)d_in[9];
  const float* pro_w   = (const float*)d_in[10];
  const float* cd_w    = (const float*)d_in[11];
  const float* co_w    = (const float*)d_in[12];
  float* out = (float*)d_out;

  char* p = (char*)d_ws;
  int4*   idx4 = (int4*)p;            p += 147456 * 16;
  float4* wt4  = (float4*)p;          p += 147456 * 16;
  ushort* feat_bf = (ushort*)p;       p += 4194304 * 2;
  ushort* wg      = (ushort*)p;       p += 9 * 589824 * 2;
  ushort* wgpio   = (ushort*)p;       p += 41472 * 2;
  ushort* wgpro   = (ushort*)p;       p += 41472 * 2;
  ushort* wgco    = (ushort*)p;       p += 34560 * 2;
  ushort* actA    = (ushort*)p;       p += 4194304 * 2;
  ushort* actB    = (ushort*)p;       p += 4194304 * 2;
  float*  off1    = (float*)p;        p += OFF_ELEMS * 4;
  float*  off2    = (float*)p;        p += OFF_ELEMS * 4;
  float2* stats   = (float2*)p;

  ushort* WG[9];
  for (int i = 0; i < 9; ++i) WG[i] = wg + (size_t)i * 589824;

  dim3 blk(256);
  tr_nhwc<<<dim3(64, 4), blk, 0, stream>>>(feature, feat_bf);
  WJobs jobs;
  const float* srcs[12] = {loc_ws, loc_ws + 589824, loc_ws + 2 * 589824,
                           cls_ws, cls_ws + 589824, cls_ws + 2 * 589824,
                           pi_w,   prd_w,           cd_w,
                           pio_w,  pro_w,           co_w};
  ushort* dsts[12] = {WG[0], WG[1], WG[2], WG[3], WG[4], WG[5],
                      WG[6], WG[7], WG[8], wgpio, wgpro, wgco};
  int couts[12] = {256,256,256,256,256,256,256,256,256,18,18,15};
  for (int i = 0; i < 12; ++i) {
    jobs.src[i] = srcs[i]; jobs.dst[i] = dsts[i]; jobs.cout[i] = couts[i];
  }
  wcvt<<<dim3(256, 9, 12), blk, 0, stream>>>(jobs);

  auto conv = [&](const ushort* in, const ushort* w, ushort* o) {
    conv_std<256, true><<<dim3(256), dim3(512), 0, stream>>>(in, w, o, 256);
  };
  auto dconv = [&](const ushort* in, const ushort* w, ushort* o) {
    conv_dfm<<<dim3(256), dim3(512), 0, stream>>>(in, w, o, idx4, wt4);
  };
  auto sconv = [&](const ushort* in, const ushort* w, float* o, int Cout) {
    conv_std<32, false><<<dim3(256), dim3(256), 0, stream>>>(in, w, o, Cout);
  };
  auto gn = [&](const ushort* in, const float* g, const float* b, ushort* o) {
    gn_stats<<<dim3(128), blk, 0, stream>>>(in, stats);
    gn_apply<<<dim3(2048), blk, 0, stream>>>(in, stats, g, b, o);
  };

  // ---- loc branch ----
  conv(feat_bf, WG[0], actA);
  gn(actA, loc_g + 0,   loc_b + 0,   actB);
  conv(actB, WG[1], actA);
  gn(actA, loc_g + 256, loc_b + 256, actB);
  conv(actB, WG[2], actA);
  gn(actA, loc_g + 512, loc_b + 512, actB);       // actB = loc (NHWC)
  conv(actB, WG[6], actA);                        // pi
  sconv(actA, wgpio, off1, 18);                   // offset1 (fp32 NCHW)
  precomp_offsets<<<dim3(576), blk, 0, stream>>>(off1, idx4, wt4);
  dconv(actB, WG[7], actA);                       // deform(loc, offset1)
  sconv(actA, wgpro, off2, 18);                   // offset2

  // ---- cls branch ----
  conv(feat_bf, WG[3], actA);
  gn(actA, cls_g + 0,   cls_b + 0,   actB);
  conv(actB, WG[4], actA);
  gn(actA, cls_g + 256, cls_b + 256, actB);
  conv(actB, WG[5], actA);
  gn(actA, cls_g + 512, cls_b + 512, actB);       // actB = clsf
  dconv(actB, WG[8], actA);                       // deform(clsf, offset1)
  sconv(actA, wgco, out + CLS_OFF, 15);           // classification (fp32 NCHW)

  // ---- rep points ----
  rp_out<<<dim3(1152), blk, 0, stream>>>(off1, off2, out);
}

// Round 8
// 929.113 us; speedup vs baseline: 1.2821x; 1.2821x over previous
//
#include <hip/hip_runtime.h>

#define PLANE 4096
#define OFF_ELEMS 294912
#define CLS_OFF   589824

typedef __attribute__((ext_vector_type(4))) float f32x4;
typedef __attribute__((ext_vector_type(8))) short bf16x8;

__device__ __forceinline__ float bf2f(ushort u) {
  union { uint u; float f; } x; x.u = ((uint)u) << 16; return x.f;
}
__device__ __forceinline__ ushort f2bf(float f) {
  union { float f; uint u; } x; x.f = f;
  return (ushort)((x.u + 0x7fffu + ((x.u >> 16) & 1u)) >> 16);
}
__device__ __forceinline__ void gload_lds16(const void* g, void* l) {
  __builtin_amdgcn_global_load_lds(
      (const __attribute__((address_space(1))) void*)g,
      (__attribute__((address_space(3))) void*)l, 16, 0, 0);
}

// ---------------------------------------------------------------------------
// Row-pipelined NHWC bf16 MFMA conv3x3 (pad 1).  One block = one output row.
// Stage row r+1 (32 KB, global_load_lds, granule XOR-swizzle) while computing
// row r's 3 kx-taps from LDS.  Double-buffered, one barrier per row.
// LDS 64 KB -> 2 blocks/CU; launch_bounds(512,2) -> 128 VGPR (NO spill; the
// (512,4) variant forced 64 VGPR and spilled 400 MB/dispatch to scratch).
// ---------------------------------------------------------------------------
template <int CO_TILE, bool OUT_BF16>
__global__ __launch_bounds__((CO_TILE == 256) ? 512 : 256, 2)
void conv_std(const ushort* __restrict__ in, const ushort* __restrict__ wg,
              void* __restrict__ outp, int Cout) {
  constexpr int WAVES = (CO_TILE == 256) ? 8 : 4;
  constexpr int WM_WAVES = (CO_TILE == 256) ? 4 : 1;
  constexpr int WN_WAVES = WAVES / WM_WAVES;       // 2 or 4
  constexpr int WM_SUB = CO_TILE / WM_WAVES;       // 64 or 32
  constexpr int MFR = WM_SUB / 16;                 // 4 or 2
  constexpr int PX_SUB = 64 / WN_WAVES;            // 32 or 16
  constexpr int NFR = PX_SUB / 16;                 // 2 or 1
  constexpr int ISS = 32 / WAVES;                  // stage issues per wave

  __shared__ __align__(16) ushort Bs[2][16384];    // 2 x 32 KB row buffers

  const int bid = blockIdx.x;
  const int r8 = bid & 7;
  const int b = r8 >> 1;
  const int y = (r8 & 1) * 32 + (bid >> 3);
  const int t = threadIdx.x;
  const int wv = t >> 6, lane = t & 63, lm = lane & 15, kg = lane >> 4;
  const int wm = (WM_WAVES == 4) ? (wv & 3) : 0;
  const int wn = (WM_WAVES == 4) ? (wv >> 2) : wv;

  const ushort* inb = in + (size_t)b * (PLANE * 256);

  int rows[3], nr = 0;
#pragma unroll
  for (int r = 0; r < 3; ++r)
    if ((unsigned)(y + r - 1) < 64u) rows[nr++] = r;

  const int pxl = lane >> 5, gd = lane & 31;
  auto stage = [&](int r, int bufi) {
    const int iy = y + r - 1;
#pragma unroll
    for (int n = 0; n < ISS; ++n) {
      int i = wv * ISS + n;
      int px = i * 2 + pxl;
      int gs = gd ^ (px & 7);
      gload_lds16(inb + ((size_t)(iy * 64 + px)) * 256 + gs * 8,
                  (char*)Bs[bufi] + i * 1024);
    }
  };

  f32x4 acc[MFR][NFR] = {};
  const ushort* wrow[MFR];
#pragma unroll
  for (int mi = 0; mi < MFR; ++mi) {
    int cor = wm * WM_SUB + mi * 16 + lm;
    if (cor > Cout - 1) cor = Cout - 1;   // clamped rows go to D rows >= Cout (unstored)
    wrow[mi] = wg + (size_t)cor * 256 + kg * 8;
  }
  const int wks = Cout * 256;

  auto compute = [&](int r, int bufi) {
    const char* buf = (const char*)Bs[bufi];
#pragma unroll
    for (int kx = 0; kx < 3; ++kx) {
      const int kk = r * 3 + kx;
      int sb[NFR], swz[NFR];
      bool bval[NFR];
#pragma unroll
      for (int ni = 0; ni < NFR; ++ni) {
        int px = wn * PX_SUB + ni * 16 + lm;
        int ix = px + kx - 1;
        bval[ni] = (unsigned)ix < 64u;
        int ixc = min(max(ix, 0), 63);
        sb[ni] = ixc * 512;
        swz[ni] = ixc & 7;
      }
#pragma unroll
      for (int cc = 0; cc < 4; ++cc) {
        bf16x8 af[MFR][2], bf[NFR][2];
#pragma unroll
        for (int mi = 0; mi < MFR; ++mi)
#pragma unroll
          for (int ks = 0; ks < 2; ++ks)
            af[mi][ks] = *(const bf16x8*)(wrow[mi] + kk * wks + cc * 64 + ks * 32);
        bf16x8 z = {};
#pragma unroll
        for (int ni = 0; ni < NFR; ++ni)
#pragma unroll
          for (int ks = 0; ks < 2; ++ks) {
            int g = (cc * 8 + ks * 4 + kg) ^ swz[ni];
            bf16x8 v = *(const bf16x8*)(buf + sb[ni] + g * 16);
            bf[ni][ks] = bval[ni] ? v : z;
          }
        __builtin_amdgcn_s_setprio(1);
#pragma unroll
        for (int mi = 0; mi < MFR; ++mi)
#pragma unroll
          for (int ni = 0; ni < NFR; ++ni)
#pragma unroll
            for (int ks = 0; ks < 2; ++ks)
              acc[mi][ni] = __builtin_amdgcn_mfma_f32_16x16x32_bf16(
                  af[mi][ks], bf[ni][ks], acc[mi][ni], 0, 0, 0);
        __builtin_amdgcn_s_setprio(0);
      }
    }
  };

  stage(rows[0], 0);
  asm volatile("s_waitcnt vmcnt(0)" ::: "memory");
  __syncthreads();
  for (int i = 0; i < nr; ++i) {
    if (i + 1 < nr) stage(rows[i + 1], (i + 1) & 1);
    compute(rows[i], i & 1);
    asm volatile("s_waitcnt vmcnt(0)" ::: "memory");
    __syncthreads();
  }

  // ---- epilogue ----
  if (OUT_BF16) {
    ushort* outb = (ushort*)outp + (size_t)b * (PLANE * 256) + (size_t)y * 64 * 256;
#pragma unroll
    for (int mi = 0; mi < MFR; ++mi)
#pragma unroll
      for (int ni = 0; ni < NFR; ++ni) {
        int px = wn * PX_SUB + ni * 16 + lm;
        int co0 = wm * WM_SUB + mi * 16 + kg * 4;
        ushort4 h;
        h.x = f2bf(acc[mi][ni][0]); h.y = f2bf(acc[mi][ni][1]);
        h.z = f2bf(acc[mi][ni][2]); h.w = f2bf(acc[mi][ni][3]);
        *(ushort4*)(outb + (size_t)px * 256 + co0) = h;
      }
  } else {
    float* o = (float*)outp;
#pragma unroll
    for (int mi = 0; mi < MFR; ++mi)
#pragma unroll
      for (int ni = 0; ni < NFR; ++ni) {
        int px = wn * PX_SUB + ni * 16 + lm;
#pragma unroll
        for (int rr = 0; rr < 4; ++rr) {
          int co = wm * WM_SUB + mi * 16 + kg * 4 + rr;
          if (co < Cout)
            o[((size_t)(b * Cout + co)) * PLANE + y * 64 + px] = acc[mi][ni][rr];
        }
      }
  }
}

// ---------------------------------------------------------------------------
// Tap-pipelined deformable conv3x3 (v1).  One blended tap-plane (32 KB)
// double-buffered: per tap, issue next tap's 16 bilinear gathers, compute
// current tap's MFMA, blend+ds_write, one barrier per tap.
// launch_bounds(512,2): 128 VGPR, no spill (this kernel needs ~128).
// ---------------------------------------------------------------------------
__global__ __launch_bounds__(512, 2) void conv_dfm(
    const ushort* __restrict__ in, const ushort* __restrict__ wg,
    ushort* __restrict__ outp, const int4* __restrict__ idx4,
    const float4* __restrict__ wt4) {
  __shared__ __align__(16) ushort Ds[2][16384];

  const int bid = blockIdx.x;
  const int r8 = bid & 7;
  const int b = r8 >> 1;
  const int y = (r8 & 1) * 32 + (bid >> 3);
  const int t = threadIdx.x;
  const int wv = t >> 6, lane = t & 63, lm = lane & 15, kg = lane >> 4;
  const int wm = wv & 3, wn = wv >> 2;
  const int spx = t >> 3, gd = t & 7;      // stage: pixel / low-granule

  const ushort* inb = in + (size_t)b * (PLANE * 256);

  int4 tA; float4 wA;                       // table for the tap being gathered
  auto ldtbl = [&](int kk) {
    int pi = ((b * 9 + kk) * 64 + y) * 64 + spx;
    tA = idx4[pi]; wA = wt4[pi];
  };

  bf16x8 g[8];                              // 8 in-flight gathers (2 cc chunks)
  auto gather = [&](int ccp) {
#pragma unroll
    for (int q = 0; q < 2; ++q) {
      int cc = ccp * 2 + q;
      const ushort* cb = inb + (cc * 8 + gd) * 8;
      g[q * 4 + 0] = *(const bf16x8*)(cb + (size_t)tA.x * 256);
      g[q * 4 + 1] = *(const bf16x8*)(cb + (size_t)tA.y * 256);
      g[q * 4 + 2] = *(const bf16x8*)(cb + (size_t)tA.z * 256);
      g[q * 4 + 3] = *(const bf16x8*)(cb + (size_t)tA.w * 256);
    }
  };
  auto blend = [&](int ccp, int nb) {
#pragma unroll
    for (int q = 0; q < 2; ++q) {
      int cc = ccp * 2 + q;
      uint4 pk; ushort* hp = (ushort*)&pk;
#pragma unroll
      for (int j = 0; j < 8; ++j) {
        float f = wA.x * bf2f(((ushort*)&g[q * 4 + 0])[j])
                + wA.y * bf2f(((ushort*)&g[q * 4 + 1])[j])
                + wA.z * bf2f(((ushort*)&g[q * 4 + 2])[j])
                + wA.w * bf2f(((ushort*)&g[q * 4 + 3])[j]);
        hp[j] = f2bf(f);
      }
      int slot = (cc * 8 + gd) ^ (spx & 7);
      *(uint4*)((char*)Ds[nb] + spx * 512 + slot * 16) = pk;
    }
  };

  f32x4 acc[4][2] = {};
  const ushort* wrow[4];
#pragma unroll
  for (int mi = 0; mi < 4; ++mi)
    wrow[mi] = wg + (size_t)(wm * 64 + mi * 16 + lm) * 256 + kg * 8;

  int pxn[2], swz[2];
#pragma unroll
  for (int ni = 0; ni < 2; ++ni) {
    pxn[ni] = (wn * 32 + ni * 16 + lm) * 512;
    swz[ni] = (wn * 32 + ni * 16 + lm) & 7;
  }

  auto compute_cc = [&](int kk, int cur, int cc) {
    bf16x8 af[4][2], bf[2][2];
#pragma unroll
    for (int mi = 0; mi < 4; ++mi)
#pragma unroll
      for (int ks = 0; ks < 2; ++ks)
        af[mi][ks] = *(const bf16x8*)(wrow[mi] + kk * 65536 + cc * 64 + ks * 32);
#pragma unroll
    for (int ni = 0; ni < 2; ++ni)
#pragma unroll
      for (int ks = 0; ks < 2; ++ks) {
        int gs = (cc * 8 + ks * 4 + kg) ^ swz[ni];
        bf[ni][ks] = *(const bf16x8*)((const char*)Ds[cur] + pxn[ni] + gs * 16);
      }
    __builtin_amdgcn_s_setprio(1);
#pragma unroll
    for (int mi = 0; mi < 4; ++mi)
#pragma unroll
      for (int ni = 0; ni < 2; ++ni)
#pragma unroll
        for (int ks = 0; ks < 2; ++ks)
          acc[mi][ni] = __builtin_amdgcn_mfma_f32_16x16x32_bf16(
              af[mi][ks], bf[ni][ks], acc[mi][ni], 0, 0, 0);
    __builtin_amdgcn_s_setprio(0);
  };

  // prologue: blend tap 0 into Ds[0]
  ldtbl(0);
  gather(0); blend(0, 0);
  gather(1); blend(1, 0);
  ldtbl(1);
  __syncthreads();

  for (int kk = 0; kk < 9; ++kk) {
    const int cur = kk & 1, nb = cur ^ 1;
    const bool pf = (kk < 8);
    if (pf) gather(0);                 // tap kk+1, cc 0-1 (uses tA = tbl kk+1)
    compute_cc(kk, cur, 0);
    compute_cc(kk, cur, 1);
    if (pf) { blend(0, nb); gather(1); }
    compute_cc(kk, cur, 2);
    compute_cc(kk, cur, 3);
    if (pf) {
      blend(1, nb);
      if (kk + 2 < 9) ldtbl(kk + 2);
    }
    __syncthreads();
  }

  ushort* outb = outp + (size_t)b * (PLANE * 256) + (size_t)y * 64 * 256;
#pragma unroll
  for (int mi = 0; mi < 4; ++mi)
#pragma unroll
    for (int ni = 0; ni < 2; ++ni) {
      int px = wn * 32 + ni * 16 + lm;
      int co0 = wm * 64 + mi * 16 + kg * 4;
      ushort4 h;
      h.x = f2bf(acc[mi][ni][0]); h.y = f2bf(acc[mi][ni][1]);
      h.z = f2bf(acc[mi][ni][2]); h.w = f2bf(acc[mi][ni][3]);
      *(ushort4*)(outb + (size_t)px * 256 + co0) = h;
    }
}

// ---------------------------------------------------------------------------
// fp32 NCHW feature -> bf16 NHWC
// ---------------------------------------------------------------------------
__global__ __launch_bounds__(256) void tr_nhwc(const float* __restrict__ src,
                                               ushort* __restrict__ dst) {
  __shared__ ushort T[64][264];
  int y = blockIdx.x, b = blockIdx.y, t = threadIdx.x;
  const float* s = src + (size_t)b * 1048576 + y * 64;
  int ci0 = t >> 2, f4 = t & 3;
#pragma unroll
  for (int cb = 0; cb < 4; ++cb) {
    int ci = cb * 64 + ci0;
#pragma unroll
    for (int l = 0; l < 4; ++l) {
      int px = (f4 + l * 4) * 4;
      float4 v = *(const float4*)(s + (size_t)ci * 4096 + px);
      T[px + 0][ci] = f2bf(v.x);
      T[px + 1][ci] = f2bf(v.y);
      T[px + 2][ci] = f2bf(v.z);
      T[px + 3][ci] = f2bf(v.w);
    }
  }
  __syncthreads();
  ushort* d = dst + (size_t)(b * 4096 + y * 64) * 256;
#pragma unroll
  for (int k = 0; k < 8; ++k) {
    int u = t + k * 256;
    int px = u >> 5, c32 = u & 31;
    uint4 vv = *(const uint4*)&T[px][c32 * 8];
    *(uint4*)(d + (size_t)px * 256 + c32 * 8) = vv;
  }
}

// ---------------------------------------------------------------------------
__global__ __launch_bounds__(256) void precomp_offsets(
    const float* __restrict__ off, int4* __restrict__ idx4,
    float4* __restrict__ wt4) {
  int tid = blockIdx.x * 256 + threadIdx.x;
  if (tid >= 4 * 9 * PLANE) return;
  int x = tid & 63, y = (tid >> 6) & 63;
  int kk = (tid >> 12) % 9;
  int b = tid / (9 * PLANE);
  float dy = off[((b * 18 + 2 * kk) * 64 + y) * 64 + x];
  float dx = off[((b * 18 + 2 * kk + 1) * 64 + y) * 64 + x];
  float sy = dy + (float)(y - 1 + kk / 3);
  float sx = dx + (float)(x - 1 + kk % 3);
  float y0f = floorf(sy), x0f = floorf(sx);
  float wy = sy - y0f, wx = sx - x0f;
  int y0 = (int)y0f, x0 = (int)x0f, y1 = y0 + 1, x1 = x0 + 1;
  float vy0 = ((unsigned)y0 < 64u) ? 1.f : 0.f;
  float vy1 = ((unsigned)y1 < 64u) ? 1.f : 0.f;
  float vx0 = ((unsigned)x0 < 64u) ? 1.f : 0.f;
  float vx1 = ((unsigned)x1 < 64u) ? 1.f : 0.f;
  int cy0 = min(max(y0, 0), 63), cy1 = min(max(y1, 0), 63);
  int cx0 = min(max(x0, 0), 63), cx1 = min(max(x1, 0), 63);
  idx4[tid] = make_int4(cy0 * 64 + cx0, cy0 * 64 + cx1,
                        cy1 * 64 + cx0, cy1 * 64 + cx1);
  wt4[tid] = make_float4((1.f - wy) * (1.f - wx) * vy0 * vx0,
                         (1.f - wy) * wx * vy0 * vx1,
                         wy * (1.f - wx) * vy1 * vx0, wy * wx * vy1 * vx1);
}

// ---------------------------------------------------------------------------
__global__ __launch_bounds__(256) void gn_stats(const ushort* __restrict__ x,
                                                float2* __restrict__ stats) {
  int bg = blockIdx.x;
  int b = bg >> 5, g = bg & 31;
  const uint4* base = (const uint4*)(x + (size_t)b * 1048576 + g * 8);
  float s = 0.f, q = 0.f;
#pragma unroll
  for (int k = 0; k < 16; ++k) {
    int p = threadIdx.x + k * 256;
    uint4 v = base[(size_t)p * 32];
    const ushort* h = (const ushort*)&v;
#pragma unroll
    for (int j = 0; j < 8; ++j) { float f = bf2f(h[j]); s += f; q += f * f; }
  }
#pragma unroll
  for (int o = 32; o; o >>= 1) { s += __shfl_xor(s, o); q += __shfl_xor(q, o); }
  __shared__ float ss[4], qq[4];
  int wid = threadIdx.x >> 6;
  if ((threadIdx.x & 63) == 0) { ss[wid] = s; qq[wid] = q; }
  __syncthreads();
  if (threadIdx.x == 0) {
    s = ss[0] + ss[1] + ss[2] + ss[3];
    q = qq[0] + qq[1] + qq[2] + qq[3];
    float m = s / 32768.f;
    float v = q / 32768.f - m * m;
    stats[bg] = make_float2(m, rsqrtf(v + 1e-5f));
  }
}

__global__ __launch_bounds__(256) void gn_apply(
    const ushort* __restrict__ x, const float2* __restrict__ stats,
    const float* __restrict__ gamma, const float* __restrict__ beta,
    ushort* __restrict__ out) {
  int i = blockIdx.x * 256 + threadIdx.x;
  uint4 v = ((const uint4*)x)[i];
  int cg = i & 31;
  int b = i >> 17;
  float2 st = stats[b * 32 + cg];
  const float4* gp = (const float4*)(gamma + cg * 8);
  const float4* bp = (const float4*)(beta + cg * 8);
  float4 g0 = gp[0], g1 = gp[1], b0 = bp[0], b1 = bp[1];
  float ga[8] = {g0.x, g0.y, g0.z, g0.w, g1.x, g1.y, g1.z, g1.w};
  float bb[8] = {b0.x, b0.y, b0.z, b0.w, b1.x, b1.y, b1.z, b1.w};
  ushort* h = (ushort*)&v;
#pragma unroll
  for (int j = 0; j < 8; ++j) {
    float a = st.y * ga[j];
    h[j] = f2bf(bf2f(h[j]) * a + (bb[j] - st.x * a));
  }
  ((uint4*)out)[i] = v;
}

// ---------------------------------------------------------------------------
struct WJobs {
  const float* src[12];
  ushort* dst[12];
  int cout[12];
};
__global__ __launch_bounds__(256) void wcvt(WJobs j) {
  int job = blockIdx.z, kk = blockIdx.y, co = blockIdx.x, ci = threadIdx.x;
  int Cout = j.cout[job];
  if (co >= Cout) return;
  j.dst[job][((size_t)kk * Cout + co) * 256 + ci] =
      f2bf(j.src[job][co * 2304 + ci * 9 + kk]);
}

// ---------------------------------------------------------------------------
__global__ __launch_bounds__(256) void rp_out(const float* __restrict__ off1,
                                              const float* __restrict__ off2,
                                              float* __restrict__ out) {
  int tid = blockIdx.x * 256 + threadIdx.x;
  if (tid >= OFF_ELEMS) return;
  int x = tid & 63, y = (tid >> 6) & 63;
  int ch = (tid >> 12) % 18;
  int k = ch >> 1;
  float base = (ch & 1) ? (float)(x + (k % 3) - 1) : (float)(y + (k / 3) - 1);
  float r1 = base + off1[tid];
  out[tid] = r1;
  out[OFF_ELEMS + tid] = r1 + off2[tid];
}

// ---------------------------------------------------------------------------
extern "C" void kernel_launch(void* const* d_in, const int* in_sizes, int n_in,
                              void* d_out, int out_size, void* d_ws,
                              size_t ws_size, hipStream_t stream) {
  (void)in_sizes; (void)n_in; (void)out_size; (void)ws_size;
  const float* feature = (const float*)d_in[0];
  const float* loc_ws  = (const float*)d_in[1];
  const float* loc_g   = (const float*)d_in[2];
  const float* loc_b   = (const float*)d_in[3];
  const float* cls_ws  = (const float*)d_in[4];
  const float* cls_g   = (const float*)d_in[5];
  const float* cls_b   = (const float*)d_in[6];
  const float* pi_w    = (const float*)d_in[7];
  const float* pio_w   = (const float*)d_in[8];
  const float* prd_w   = (const float*)d_in[9];
  const float* pro_w   = (const float*)d_in[10];
  const float* cd_w    = (const float*)d_in[11];
  const float* co_w    = (const float*)d_in[12];
  float* out = (float*)d_out;

  char* p = (char*)d_ws;
  int4*   idx4 = (int4*)p;            p += 147456 * 16;
  float4* wt4  = (float4*)p;          p += 147456 * 16;
  ushort* feat_bf = (ushort*)p;       p += 4194304 * 2;
  ushort* wg      = (ushort*)p;       p += 9 * 589824 * 2;
  ushort* wgpio   = (ushort*)p;       p += 41472 * 2;
  ushort* wgpro   = (ushort*)p;       p += 41472 * 2;
  ushort* wgco    = (ushort*)p;       p += 34560 * 2;
  ushort* actA    = (ushort*)p;       p += 4194304 * 2;
  ushort* actB    = (ushort*)p;       p += 4194304 * 2;
  float*  off1    = (float*)p;        p += OFF_ELEMS * 4;
  float*  off2    = (float*)p;        p += OFF_ELEMS * 4;
  float2* stats   = (float2*)p;

  ushort* WG[9];
  for (int i = 0; i < 9; ++i) WG[i] = wg + (size_t)i * 589824;

  dim3 blk(256);
  tr_nhwc<<<dim3(64, 4), blk, 0, stream>>>(feature, feat_bf);
  WJobs jobs;
  const float* srcs[12] = {loc_ws, loc_ws + 589824, loc_ws + 2 * 589824,
                           cls_ws, cls_ws + 589824, cls_ws + 2 * 589824,
                           pi_w,   prd_w,           cd_w,
                           pio_w,  pro_w,           co_w};
  ushort* dsts[12] = {WG[0], WG[1], WG[2], WG[3], WG[4], WG[5],
                      WG[6], WG[7], WG[8], wgpio, wgpro, wgco};
  int couts[12] = {256,256,256,256,256,256,256,256,256,18,18,15};
  for (int i = 0; i < 12; ++i) {
    jobs.src[i] = srcs[i]; jobs.dst[i] = dsts[i]; jobs.cout[i] = couts[i];
  }
  wcvt<<<dim3(256, 9, 12), blk, 0, stream>>>(jobs);

  auto conv = [&](const ushort* in, const ushort* w, ushort* o) {
    conv_std<256, true><<<dim3(256), dim3(512), 0, stream>>>(in, w, o, 256);
  };
  auto dconv = [&](const ushort* in, const ushort* w, ushort* o) {
    conv_dfm<<<dim3(256), dim3(512), 0, stream>>>(in, w, o, idx4, wt4);
  };
  auto sconv = [&](const ushort* in, const ushort* w, float* o, int Cout) {
    conv_std<32, false><<<dim3(256), dim3(256), 0, stream>>>(in, w, o, Cout);
  };
  auto gn = [&](const ushort* in, const float* g, const float* b, ushort* o) {
    gn_stats<<<dim3(128), blk, 0, stream>>>(in, stats);
    gn_apply<<<dim3(2048), blk, 0, stream>>>(in, stats, g, b, o);
  };

  // ---- loc branch ----
  conv(feat_bf, WG[0], actA);
  gn(actA, loc_g + 0,   loc_b + 0,   actB);
  conv(actB, WG[1], actA);
  gn(actA, loc_g + 256, loc_b + 256, actB);
  conv(actB, WG[2], actA);
  gn(actA, loc_g + 512, loc_b + 512, actB);       // actB = loc (NHWC)
  conv(actB, WG[6], actA);                        // pi
  sconv(actA, wgpio, off1, 18);                   // offset1 (fp32 NCHW)
  precomp_offsets<<<dim3(576), blk, 0, stream>>>(off1, idx4, wt4);
  dconv(actB, WG[7], actA);                       // deform(loc, offset1)
  sconv(actA, wgpro, off2, 18);                   // offset2

  // ---- cls branch ----
  conv(feat_bf, WG[3], actA);
  gn(actA, cls_g + 0,   cls_b + 0,   actB);
  conv(actB, WG[4], actA);
  gn(actA, cls_g + 256, cls_b + 256, actB);
  conv(actB, WG[5], actA);
  gn(actA, cls_g + 512, cls_b + 512, actB);       // actB = clsf
  dconv(actB, WG[8], actA);                       // deform(clsf, offset1)
  sconv(actA, wgco, out + CLS_OFF, 15);           // classification (fp32 NCHW)

  // ---- rep points ----
  rp_out<<<dim3(1152), blk, 0, stream>>>(off1, off2, out);
}

// Round 9
// 875.073 us; speedup vs baseline: 1.3612x; 1.0618x over previous
//
#include <hip/hip_runtime.h>

#define PLANE 4096
#define OFF_ELEMS 294912
#define CLS_OFF   589824

typedef __attribute__((ext_vector_type(4))) float f32x4;
typedef __attribute__((ext_vector_type(8))) short bf16x8;

__device__ __forceinline__ float bf2f(ushort u) {
  union { uint u; float f; } x; x.u = ((uint)u) << 16; return x.f;
}
__device__ __forceinline__ ushort f2bf(float f) {
  union { float f; uint u; } x; x.f = f;
  return (ushort)((x.u + 0x7fffu + ((x.u >> 16) & 1u)) >> 16);
}
__device__ __forceinline__ void gload_lds16(const void* g, void* l) {
  __builtin_amdgcn_global_load_lds(
      (const __attribute__((address_space(1))) void*)g,
      (__attribute__((address_space(3))) void*)l, 16, 0, 0);
}

// ---------------------------------------------------------------------------
// Row-pipelined NHWC bf16 MFMA conv3x3 (pad 1), PAIRED: grid 512 runs two
// independent convs (sub = bid>>8) -> 2 blocks/CU, 16 waves/CU at 128 VGPR.
// Stage row r+1 (32 KB global_load_lds, granule XOR-swizzle) while computing
// row r's 3 kx-taps.  One barrier per row.  launch_bounds(512,2)=128 VGPR
// (NO spill; (512,4)->64 VGPR spilled 400 MB/dispatch in round 7).
// ---------------------------------------------------------------------------
template <int CO_TILE, bool OUT_BF16>
__global__ __launch_bounds__((CO_TILE == 256) ? 512 : 256, 2)
void conv_std(const ushort* __restrict__ in0, const ushort* __restrict__ in1,
              const ushort* __restrict__ w0, const ushort* __restrict__ w1,
              void* __restrict__ o0, void* __restrict__ o1,
              int cout0, int cout1) {
  constexpr int WAVES = (CO_TILE == 256) ? 8 : 4;
  constexpr int WM_WAVES = (CO_TILE == 256) ? 4 : 1;
  constexpr int WN_WAVES = WAVES / WM_WAVES;       // 2 or 4
  constexpr int WM_SUB = CO_TILE / WM_WAVES;       // 64 or 32
  constexpr int MFR = WM_SUB / 16;                 // 4 or 2
  constexpr int PX_SUB = 64 / WN_WAVES;            // 32 or 16
  constexpr int NFR = PX_SUB / 16;                 // 2 or 1
  constexpr int ISS = 32 / WAVES;                  // stage issues per wave

  __shared__ __align__(16) ushort Bs[2][16384];    // 2 x 32 KB row buffers

  const int sub = blockIdx.x >> 8;
  const ushort* in = sub ? in1 : in0;
  const ushort* wg = sub ? w1 : w0;
  void* outp = sub ? o1 : o0;
  const int Cout = sub ? cout1 : cout0;

  const int bid = blockIdx.x & 255;
  const int r8 = bid & 7;
  const int b = r8 >> 1;
  const int y = (r8 & 1) * 32 + (bid >> 3);
  const int t = threadIdx.x;
  const int wv = t >> 6, lane = t & 63, lm = lane & 15, kg = lane >> 4;
  const int wm = (WM_WAVES == 4) ? (wv & 3) : 0;
  const int wn = (WM_WAVES == 4) ? (wv >> 2) : wv;

  const ushort* inb = in + (size_t)b * (PLANE * 256);

  int rows[3], nr = 0;
#pragma unroll
  for (int r = 0; r < 3; ++r)
    if ((unsigned)(y + r - 1) < 64u) rows[nr++] = r;

  const int pxl = lane >> 5, gd = lane & 31;
  auto stage = [&](int r, int bufi) {
    const int iy = y + r - 1;
#pragma unroll
    for (int n = 0; n < ISS; ++n) {
      int i = wv * ISS + n;
      int px = i * 2 + pxl;
      int gs = gd ^ (px & 7);
      gload_lds16(inb + ((size_t)(iy * 64 + px)) * 256 + gs * 8,
                  (char*)Bs[bufi] + i * 1024);
    }
  };

  f32x4 acc[MFR][NFR] = {};
  const ushort* wrow[MFR];
#pragma unroll
  for (int mi = 0; mi < MFR; ++mi) {
    int cor = wm * WM_SUB + mi * 16 + lm;
    if (cor > Cout - 1) cor = Cout - 1;   // clamped rows go to D rows >= Cout (unstored)
    wrow[mi] = wg + (size_t)cor * 256 + kg * 8;
  }
  const int wks = Cout * 256;

  auto compute = [&](int r, int bufi) {
    const char* buf = (const char*)Bs[bufi];
#pragma unroll
    for (int kx = 0; kx < 3; ++kx) {
      const int kk = r * 3 + kx;
      int sb[NFR], swz[NFR];
      bool bval[NFR];
#pragma unroll
      for (int ni = 0; ni < NFR; ++ni) {
        int px = wn * PX_SUB + ni * 16 + lm;
        int ix = px + kx - 1;
        bval[ni] = (unsigned)ix < 64u;
        int ixc = min(max(ix, 0), 63);
        sb[ni] = ixc * 512;
        swz[ni] = ixc & 7;
      }
#pragma unroll
      for (int cc = 0; cc < 4; ++cc) {
        bf16x8 af[MFR][2], bf[NFR][2];
#pragma unroll
        for (int mi = 0; mi < MFR; ++mi)
#pragma unroll
          for (int ks = 0; ks < 2; ++ks)
            af[mi][ks] = *(const bf16x8*)(wrow[mi] + kk * wks + cc * 64 + ks * 32);
        bf16x8 z = {};
#pragma unroll
        for (int ni = 0; ni < NFR; ++ni)
#pragma unroll
          for (int ks = 0; ks < 2; ++ks) {
            int g = (cc * 8 + ks * 4 + kg) ^ swz[ni];
            bf16x8 v = *(const bf16x8*)(buf + sb[ni] + g * 16);
            bf[ni][ks] = bval[ni] ? v : z;
          }
        __builtin_amdgcn_s_setprio(1);
#pragma unroll
        for (int mi = 0; mi < MFR; ++mi)
#pragma unroll
          for (int ni = 0; ni < NFR; ++ni)
#pragma unroll
            for (int ks = 0; ks < 2; ++ks)
              acc[mi][ni] = __builtin_amdgcn_mfma_f32_16x16x32_bf16(
                  af[mi][ks], bf[ni][ks], acc[mi][ni], 0, 0, 0);
        __builtin_amdgcn_s_setprio(0);
      }
    }
  };

  stage(rows[0], 0);
  asm volatile("s_waitcnt vmcnt(0)" ::: "memory");
  __syncthreads();
  for (int i = 0; i < nr; ++i) {
    if (i + 1 < nr) stage(rows[i + 1], (i + 1) & 1);
    compute(rows[i], i & 1);
    asm volatile("s_waitcnt vmcnt(0)" ::: "memory");
    __syncthreads();
  }

  // ---- epilogue ----
  if (OUT_BF16) {
    ushort* outb = (ushort*)outp + (size_t)b * (PLANE * 256) + (size_t)y * 64 * 256;
#pragma unroll
    for (int mi = 0; mi < MFR; ++mi)
#pragma unroll
      for (int ni = 0; ni < NFR; ++ni) {
        int px = wn * PX_SUB + ni * 16 + lm;
        int co0 = wm * WM_SUB + mi * 16 + kg * 4;
        ushort4 h;
        h.x = f2bf(acc[mi][ni][0]); h.y = f2bf(acc[mi][ni][1]);
        h.z = f2bf(acc[mi][ni][2]); h.w = f2bf(acc[mi][ni][3]);
        *(ushort4*)(outb + (size_t)px * 256 + co0) = h;
      }
  } else {
    float* o = (float*)outp;
#pragma unroll
    for (int mi = 0; mi < MFR; ++mi)
#pragma unroll
      for (int ni = 0; ni < NFR; ++ni) {
        int px = wn * PX_SUB + ni * 16 + lm;
#pragma unroll
        for (int rr = 0; rr < 4; ++rr) {
          int co = wm * WM_SUB + mi * 16 + kg * 4 + rr;
          if (co < Cout)
            o[((size_t)(b * Cout + co)) * PLANE + y * 64 + px] = acc[mi][ni][rr];
        }
      }
  }
}

// ---------------------------------------------------------------------------
// Tap-pipelined deformable conv3x3 (v1), PAIRED (grid 512, sub = bid>>8).
// Both jobs share the same precomputed offset tables (same offset1).
// ---------------------------------------------------------------------------
__global__ __launch_bounds__(512, 2) void conv_dfm(
    const ushort* __restrict__ in0, const ushort* __restrict__ in1,
    const ushort* __restrict__ w0, const ushort* __restrict__ w1,
    ushort* __restrict__ o0, ushort* __restrict__ o1,
    const int4* __restrict__ idx4, const float4* __restrict__ wt4) {
  __shared__ __align__(16) ushort Ds[2][16384];

  const int sub = blockIdx.x >> 8;
  const ushort* in = sub ? in1 : in0;
  const ushort* wg = sub ? w1 : w0;
  ushort* outp = sub ? o1 : o0;

  const int bid = blockIdx.x & 255;
  const int r8 = bid & 7;
  const int b = r8 >> 1;
  const int y = (r8 & 1) * 32 + (bid >> 3);
  const int t = threadIdx.x;
  const int wv = t >> 6, lane = t & 63, lm = lane & 15, kg = lane >> 4;
  const int wm = wv & 3, wn = wv >> 2;
  const int spx = t >> 3, gd = t & 7;      // stage: pixel / low-granule

  const ushort* inb = in + (size_t)b * (PLANE * 256);

  int4 tA; float4 wA;                       // table for the tap being gathered
  auto ldtbl = [&](int kk) {
    int pi = ((b * 9 + kk) * 64 + y) * 64 + spx;
    tA = idx4[pi]; wA = wt4[pi];
  };

  bf16x8 g[8];                              // 8 in-flight gathers (2 cc chunks)
  auto gather = [&](int ccp) {
#pragma unroll
    for (int q = 0; q < 2; ++q) {
      int cc = ccp * 2 + q;
      const ushort* cb = inb + (cc * 8 + gd) * 8;
      g[q * 4 + 0] = *(const bf16x8*)(cb + (size_t)tA.x * 256);
      g[q * 4 + 1] = *(const bf16x8*)(cb + (size_t)tA.y * 256);
      g[q * 4 + 2] = *(const bf16x8*)(cb + (size_t)tA.z * 256);
      g[q * 4 + 3] = *(const bf16x8*)(cb + (size_t)tA.w * 256);
    }
  };
  auto blend = [&](int ccp, int nb) {
#pragma unroll
    for (int q = 0; q < 2; ++q) {
      int cc = ccp * 2 + q;
      uint4 pk; ushort* hp = (ushort*)&pk;
#pragma unroll
      for (int j = 0; j < 8; ++j) {
        float f = wA.x * bf2f(((ushort*)&g[q * 4 + 0])[j])
                + wA.y * bf2f(((ushort*)&g[q * 4 + 1])[j])
                + wA.z * bf2f(((ushort*)&g[q * 4 + 2])[j])
                + wA.w * bf2f(((ushort*)&g[q * 4 + 3])[j]);
        hp[j] = f2bf(f);
      }
      int slot = (cc * 8 + gd) ^ (spx & 7);
      *(uint4*)((char*)Ds[nb] + spx * 512 + slot * 16) = pk;
    }
  };

  f32x4 acc[4][2] = {};
  const ushort* wrow[4];
#pragma unroll
  for (int mi = 0; mi < 4; ++mi)
    wrow[mi] = wg + (size_t)(wm * 64 + mi * 16 + lm) * 256 + kg * 8;

  int pxn[2], swz[2];
#pragma unroll
  for (int ni = 0; ni < 2; ++ni) {
    pxn[ni] = (wn * 32 + ni * 16 + lm) * 512;
    swz[ni] = (wn * 32 + ni * 16 + lm) & 7;
  }

  auto compute_cc = [&](int kk, int cur, int cc) {
    bf16x8 af[4][2], bf[2][2];
#pragma unroll
    for (int mi = 0; mi < 4; ++mi)
#pragma unroll
      for (int ks = 0; ks < 2; ++ks)
        af[mi][ks] = *(const bf16x8*)(wrow[mi] + kk * 65536 + cc * 64 + ks * 32);
#pragma unroll
    for (int ni = 0; ni < 2; ++ni)
#pragma unroll
      for (int ks = 0; ks < 2; ++ks) {
        int gs = (cc * 8 + ks * 4 + kg) ^ swz[ni];
        bf[ni][ks] = *(const bf16x8*)((const char*)Ds[cur] + pxn[ni] + gs * 16);
      }
    __builtin_amdgcn_s_setprio(1);
#pragma unroll
    for (int mi = 0; mi < 4; ++mi)
#pragma unroll
      for (int ni = 0; ni < 2; ++ni)
#pragma unroll
        for (int ks = 0; ks < 2; ++ks)
          acc[mi][ni] = __builtin_amdgcn_mfma_f32_16x16x32_bf16(
              af[mi][ks], bf[ni][ks], acc[mi][ni], 0, 0, 0);
    __builtin_amdgcn_s_setprio(0);
  };

  // prologue: blend tap 0 into Ds[0]
  ldtbl(0);
  gather(0); blend(0, 0);
  gather(1); blend(1, 0);
  ldtbl(1);
  __syncthreads();

  for (int kk = 0; kk < 9; ++kk) {
    const int cur = kk & 1, nb = cur ^ 1;
    const bool pf = (kk < 8);
    if (pf) gather(0);                 // tap kk+1, cc 0-1 (uses tA = tbl kk+1)
    compute_cc(kk, cur, 0);
    compute_cc(kk, cur, 1);
    if (pf) { blend(0, nb); gather(1); }
    compute_cc(kk, cur, 2);
    compute_cc(kk, cur, 3);
    if (pf) {
      blend(1, nb);
      if (kk + 2 < 9) ldtbl(kk + 2);
    }
    __syncthreads();
  }

  ushort* outb = outp + (size_t)b * (PLANE * 256) + (size_t)y * 64 * 256;
#pragma unroll
  for (int mi = 0; mi < 4; ++mi)
#pragma unroll
    for (int ni = 0; ni < 2; ++ni) {
      int px = wn * 32 + ni * 16 + lm;
      int co0 = wm * 64 + mi * 16 + kg * 4;
      ushort4 h;
      h.x = f2bf(acc[mi][ni][0]); h.y = f2bf(acc[mi][ni][1]);
      h.z = f2bf(acc[mi][ni][2]); h.w = f2bf(acc[mi][ni][3]);
      *(ushort4*)(outb + (size_t)px * 256 + co0) = h;
    }
}

// ---------------------------------------------------------------------------
// fp32 NCHW feature -> bf16 NHWC
// ---------------------------------------------------------------------------
__global__ __launch_bounds__(256) void tr_nhwc(const float* __restrict__ src,
                                               ushort* __restrict__ dst) {
  __shared__ ushort T[64][264];
  int y = blockIdx.x, b = blockIdx.y, t = threadIdx.x;
  const float* s = src + (size_t)b * 1048576 + y * 64;
  int ci0 = t >> 2, f4 = t & 3;
#pragma unroll
  for (int cb = 0; cb < 4; ++cb) {
    int ci = cb * 64 + ci0;
#pragma unroll
    for (int l = 0; l < 4; ++l) {
      int px = (f4 + l * 4) * 4;
      float4 v = *(const float4*)(s + (size_t)ci * 4096 + px);
      T[px + 0][ci] = f2bf(v.x);
      T[px + 1][ci] = f2bf(v.y);
      T[px + 2][ci] = f2bf(v.z);
      T[px + 3][ci] = f2bf(v.w);
    }
  }
  __syncthreads();
  ushort* d = dst + (size_t)(b * 4096 + y * 64) * 256;
#pragma unroll
  for (int k = 0; k < 8; ++k) {
    int u = t + k * 256;
    int px = u >> 5, c32 = u & 31;
    uint4 vv = *(const uint4*)&T[px][c32 * 8];
    *(uint4*)(d + (size_t)px * 256 + c32 * 8) = vv;
  }
}

// ---------------------------------------------------------------------------
__global__ __launch_bounds__(256) void precomp_offsets(
    const float* __restrict__ off, int4* __restrict__ idx4,
    float4* __restrict__ wt4) {
  int tid = blockIdx.x * 256 + threadIdx.x;
  if (tid >= 4 * 9 * PLANE) return;
  int x = tid & 63, y = (tid >> 6) & 63;
  int kk = (tid >> 12) % 9;
  int b = tid / (9 * PLANE);
  float dy = off[((b * 18 + 2 * kk) * 64 + y) * 64 + x];
  float dx = off[((b * 18 + 2 * kk + 1) * 64 + y) * 64 + x];
  float sy = dy + (float)(y - 1 + kk / 3);
  float sx = dx + (float)(x - 1 + kk % 3);
  float y0f = floorf(sy), x0f = floorf(sx);
  float wy = sy - y0f, wx = sx - x0f;
  int y0 = (int)y0f, x0 = (int)x0f, y1 = y0 + 1, x1 = x0 + 1;
  float vy0 = ((unsigned)y0 < 64u) ? 1.f : 0.f;
  float vy1 = ((unsigned)y1 < 64u) ? 1.f : 0.f;
  float vx0 = ((unsigned)x0 < 64u) ? 1.f : 0.f;
  float vx1 = ((unsigned)x1 < 64u) ? 1.f : 0.f;
  int cy0 = min(max(y0, 0), 63), cy1 = min(max(y1, 0), 63);
  int cx0 = min(max(x0, 0), 63), cx1 = min(max(x1, 0), 63);
  idx4[tid] = make_int4(cy0 * 64 + cx0, cy0 * 64 + cx1,
                        cy1 * 64 + cx0, cy1 * 64 + cx1);
  wt4[tid] = make_float4((1.f - wy) * (1.f - wx) * vy0 * vx0,
                         (1.f - wy) * wx * vy0 * vx1,
                         wy * (1.f - wx) * vy1 * vx0, wy * wx * vy1 * vx1);
}

// ---------------------------------------------------------------------------
// GroupNorm, PAIRED: stats grid 256 (sub = bg>>7), apply grid 4096 (sub by idx)
// ---------------------------------------------------------------------------
__global__ __launch_bounds__(256) void gn_stats(const ushort* __restrict__ x0,
                                                const ushort* __restrict__ x1,
                                                float2* __restrict__ stats) {
  int bgg = blockIdx.x;
  int sub = bgg >> 7, bg = bgg & 127;
  const ushort* x = sub ? x1 : x0;
  int b = bg >> 5, g = bg & 31;
  const uint4* base = (const uint4*)(x + (size_t)b * 1048576 + g * 8);
  float s = 0.f, q = 0.f;
#pragma unroll
  for (int k = 0; k < 16; ++k) {
    int p = threadIdx.x + k * 256;
    uint4 v = base[(size_t)p * 32];
    const ushort* h = (const ushort*)&v;
#pragma unroll
    for (int j = 0; j < 8; ++j) { float f = bf2f(h[j]); s += f; q += f * f; }
  }
#pragma unroll
  for (int o = 32; o; o >>= 1) { s += __shfl_xor(s, o); q += __shfl_xor(q, o); }
  __shared__ float ss[4], qq[4];
  int wid = threadIdx.x >> 6;
  if ((threadIdx.x & 63) == 0) { ss[wid] = s; qq[wid] = q; }
  __syncthreads();
  if (threadIdx.x == 0) {
    s = ss[0] + ss[1] + ss[2] + ss[3];
    q = qq[0] + qq[1] + qq[2] + qq[3];
    float m = s / 32768.f;
    float v = q / 32768.f - m * m;
    stats[bgg] = make_float2(m, rsqrtf(v + 1e-5f));
  }
}

__global__ __launch_bounds__(256) void gn_apply(
    const ushort* __restrict__ x0, const ushort* __restrict__ x1,
    const float2* __restrict__ stats,
    const float* __restrict__ ga0, const float* __restrict__ be0,
    const float* __restrict__ ga1, const float* __restrict__ be1,
    ushort* __restrict__ o0, ushort* __restrict__ o1) {
  int i = blockIdx.x * 256 + threadIdx.x;   // uint4 index over both tensors
  int sub = i >> 19, il = i & 524287;
  const ushort* x = sub ? x1 : x0;
  const float* gamma = sub ? ga1 : ga0;
  const float* beta = sub ? be1 : be0;
  ushort* out = sub ? o1 : o0;
  uint4 v = ((const uint4*)x)[il];
  int cg = il & 31;
  int b = il >> 17;
  float2 st = stats[sub * 128 + b * 32 + cg];
  const float4* gp = (const float4*)(gamma + cg * 8);
  const float4* bp = (const float4*)(beta + cg * 8);
  float4 g0 = gp[0], g1 = gp[1], b0 = bp[0], b1 = bp[1];
  float ga[8] = {g0.x, g0.y, g0.z, g0.w, g1.x, g1.y, g1.z, g1.w};
  float bb[8] = {b0.x, b0.y, b0.z, b0.w, b1.x, b1.y, b1.z, b1.w};
  ushort* h = (ushort*)&v;
#pragma unroll
  for (int j = 0; j < 8; ++j) {
    float a = st.y * ga[j];
    h[j] = f2bf(bf2f(h[j]) * a + (bb[j] - st.x * a));
  }
  ((uint4*)out)[il] = v;
}

// ---------------------------------------------------------------------------
struct WJobs {
  const float* src[12];
  ushort* dst[12];
  int cout[12];
};
__global__ __launch_bounds__(256) void wcvt(WJobs j) {
  int job = blockIdx.z, kk = blockIdx.y, co = blockIdx.x, ci = threadIdx.x;
  int Cout = j.cout[job];
  if (co >= Cout) return;
  j.dst[job][((size_t)kk * Cout + co) * 256 + ci] =
      f2bf(j.src[job][co * 2304 + ci * 9 + kk]);
}

// ---------------------------------------------------------------------------
__global__ __launch_bounds__(256) void rp_out(const float* __restrict__ off1,
                                              const float* __restrict__ off2,
                                              float* __restrict__ out) {
  int tid = blockIdx.x * 256 + threadIdx.x;
  if (tid >= OFF_ELEMS) return;
  int x = tid & 63, y = (tid >> 6) & 63;
  int ch = (tid >> 12) % 18;
  int k = ch >> 1;
  float base = (ch & 1) ? (float)(x + (k % 3) - 1) : (float)(y + (k / 3) - 1);
  float r1 = base + off1[tid];
  out[tid] = r1;
  out[OFF_ELEMS + tid] = r1 + off2[tid];
}

// ---------------------------------------------------------------------------
extern "C" void kernel_launch(void* const* d_in, const int* in_sizes, int n_in,
                              void* d_out, int out_size, void* d_ws,
                              size_t ws_size, hipStream_t stream) {
  (void)in_sizes; (void)n_in; (void)out_size; (void)ws_size;
  const float* feature = (const float*)d_in[0];
  const float* loc_ws  = (const float*)d_in[1];
  const float* loc_g   = (const float*)d_in[2];
  const float* loc_b   = (const float*)d_in[3];
  const float* cls_ws  = (const float*)d_in[4];
  const float* cls_g   = (const float*)d_in[5];
  const float* cls_b   = (const float*)d_in[6];
  const float* pi_w    = (const float*)d_in[7];
  const float* pio_w   = (const float*)d_in[8];
  const float* prd_w   = (const float*)d_in[9];
  const float* pro_w   = (const float*)d_in[10];
  const float* cd_w    = (const float*)d_in[11];
  const float* co_w    = (const float*)d_in[12];
  float* out = (float*)d_out;

  char* p = (char*)d_ws;
  int4*   idx4 = (int4*)p;            p += 147456 * 16;
  float4* wt4  = (float4*)p;          p += 147456 * 16;
  ushort* feat_bf = (ushort*)p;       p += 4194304 * 2;
  ushort* wg      = (ushort*)p;       p += 9 * 589824 * 2;
  ushort* wgpio   = (ushort*)p;       p += 41472 * 2;
  ushort* wgpro   = (ushort*)p;       p += 41472 * 2;
  ushort* wgco    = (ushort*)p;       p += 34560 * 2;
  ushort* aL      = (ushort*)p;       p += 4194304 * 2;
  ushort* bL      = (ushort*)p;       p += 4194304 * 2;
  ushort* aC      = (ushort*)p;       p += 4194304 * 2;
  ushort* bC      = (ushort*)p;       p += 4194304 * 2;
  float*  off1    = (float*)p;        p += OFF_ELEMS * 4;
  float*  off2    = (float*)p;        p += OFF_ELEMS * 4;
  float2* stats   = (float2*)p;       p += 256 * 8;

  ushort* WG[9];
  for (int i = 0; i < 9; ++i) WG[i] = wg + (size_t)i * 589824;

  dim3 blk(256);
  tr_nhwc<<<dim3(64, 4), blk, 0, stream>>>(feature, feat_bf);
  WJobs jobs;
  const float* srcs[12] = {loc_ws, loc_ws + 589824, loc_ws + 2 * 589824,
                           cls_ws, cls_ws + 589824, cls_ws + 2 * 589824,
                           pi_w,   prd_w,           cd_w,
                           pio_w,  pro_w,           co_w};
  ushort* dsts[12] = {WG[0], WG[1], WG[2], WG[3], WG[4], WG[5],
                      WG[6], WG[7], WG[8], wgpio, wgpro, wgco};
  int couts[12] = {256,256,256,256,256,256,256,256,256,18,18,15};
  for (int i = 0; i < 12; ++i) {
    jobs.src[i] = srcs[i]; jobs.dst[i] = dsts[i]; jobs.cout[i] = couts[i];
  }
  wcvt<<<dim3(256, 9, 12), blk, 0, stream>>>(jobs);

  // paired big conv (grid 512 -> 2 blocks/CU)
  auto conv2 = [&](const ushort* i0, const ushort* w0, ushort* o0,
                   const ushort* i1, const ushort* w1, ushort* o1) {
    conv_std<256, true><<<dim3(512), dim3(512), 0, stream>>>(
        i0, i1, w0, w1, o0, o1, 256, 256);
  };
  auto conv1 = [&](const ushort* i0, const ushort* w0, ushort* o0) {
    conv_std<256, true><<<dim3(256), dim3(512), 0, stream>>>(
        i0, i0, w0, w0, o0, o0, 256, 256);
  };
  auto dconv2 = [&](const ushort* i0, const ushort* w0, ushort* o0,
                    const ushort* i1, const ushort* w1, ushort* o1) {
    conv_dfm<<<dim3(512), dim3(512), 0, stream>>>(i0, i1, w0, w1, o0, o1,
                                                  idx4, wt4);
  };
  auto sconv2 = [&](const ushort* i0, const ushort* w0, float* o0, int c0,
                    const ushort* i1, const ushort* w1, float* o1, int c1) {
    conv_std<32, false><<<dim3(512), dim3(256), 0, stream>>>(
        i0, i1, w0, w1, o0, o1, c0, c1);
  };
  auto sconv1 = [&](const ushort* i0, const ushort* w0, float* o0, int c0) {
    conv_std<32, false><<<dim3(256), dim3(256), 0, stream>>>(
        i0, i0, w0, w0, o0, o0, c0, c0);
  };
  auto gn2 = [&](const ushort* x0, const float* g0, const float* e0, ushort* o0,
                 const ushort* x1, const float* g1, const float* e1, ushort* o1) {
    gn_stats<<<dim3(256), blk, 0, stream>>>(x0, x1, stats);
    gn_apply<<<dim3(4096), blk, 0, stream>>>(x0, x1, stats, g0, e0, g1, e1,
                                             o0, o1);
  };

  // ---- trunk: loc & cls paired ----
  conv2(feat_bf, WG[0], aL, feat_bf, WG[3], aC);
  gn2(aL, loc_g + 0, loc_b + 0, bL, aC, cls_g + 0, cls_b + 0, bC);
  conv2(bL, WG[1], aL, bC, WG[4], aC);
  gn2(aL, loc_g + 256, loc_b + 256, bL, aC, cls_g + 256, cls_b + 256, bC);
  conv2(bL, WG[2], aL, bC, WG[5], aC);
  gn2(aL, loc_g + 512, loc_b + 512, bL, aC, cls_g + 512, cls_b + 512, bC);
  // bL = loc, bC = clsf

  // ---- offset head (loc-only) ----
  conv1(bL, WG[6], aL);                            // pi
  sconv1(aL, wgpio, off1, 18);                     // offset1 (fp32 NCHW)
  precomp_offsets<<<dim3(576), blk, 0, stream>>>(off1, idx4, wt4);

  // ---- paired deform + paired small convs ----
  dconv2(bL, WG[7], aL, bC, WG[8], aC);            // deform(loc) | deform(clsf)
  sconv2(aL, wgpro, off2, 18, aC, wgco, out + CLS_OFF, 15);

  // ---- rep points ----
  rp_out<<<dim3(1152), blk, 0, stream>>>(off1, off2, out);
}

// Round 10
// 696.061 us; speedup vs baseline: 1.7113x; 1.2572x over previous
//
#include <hip/hip_runtime.h>

#define PLANE 4096
#define OFF_ELEMS 294912
#define CLS_OFF   589824

typedef __attribute__((ext_vector_type(4))) float f32x4;
typedef __attribute__((ext_vector_type(8))) short bf16x8;

__device__ __forceinline__ float bf2f(ushort u) {
  union { uint u; float f; } x; x.u = ((uint)u) << 16; return x.f;
}
__device__ __forceinline__ ushort f2bf(float f) {
  union { float f; uint u; } x; x.f = f;
  return (ushort)((x.u + 0x7fffu + ((x.u >> 16) & 1u)) >> 16);
}
__device__ __forceinline__ void gload_lds16(const void* g, void* l) {
  __builtin_amdgcn_global_load_lds(
      (const __attribute__((address_space(1))) void*)g,
      (__attribute__((address_space(3))) void*)l, 16, 0, 0);
}

// ---------------------------------------------------------------------------
// 2-row NHWC bf16 MFMA conv3x3 (pad 1).  Block = 256co (or 32co) x 2 output
// rows.  Waves split co x output-row (not px) -> each weight fragment is
// reused across the FULL 64-px row, halving L2 A-traffic per output.
// 4 pipeline steps over input rows y0-1..y0+2, rolling 2x32KB LDS buffers,
// one barrier per step.  Paired jobs: sub = (bid >= 128).
// ---------------------------------------------------------------------------
template <int CO_TILE, bool OUT_BF16>
__global__ __launch_bounds__((CO_TILE == 256) ? 512 : 256, 1)
void conv_std2(const ushort* __restrict__ in0, const ushort* __restrict__ in1,
               const ushort* __restrict__ w0, const ushort* __restrict__ w1,
               void* __restrict__ o0, void* __restrict__ o1,
               int cout0, int cout1) {
  constexpr int THREADS = (CO_TILE == 256) ? 512 : 256;
  constexpr int WAVES = THREADS / 64;
  constexpr int MFR = (CO_TILE == 256) ? 4 : 2;   // 64 or 32 co per wave
  constexpr int NFR = (CO_TILE == 256) ? 4 : 2;   // 64 or 32 px per wave
  constexpr int IPW = 32 / WAVES;                 // 1KB stage chunks per wave

  __shared__ __align__(16) ushort Bs[2][16384];   // rolling row buffers

  const int sub = (blockIdx.x >= 128);
  const ushort* in = sub ? in1 : in0;
  const ushort* wg = sub ? w1 : w0;
  void* outp = sub ? o1 : o0;
  const int Cout = sub ? cout1 : cout0;

  const int bid7 = blockIdx.x & 127;
  const int r8 = bid7 & 7;
  const int b = r8 >> 1;
  const int y0 = ((r8 & 1) * 16 + (bid7 >> 3)) * 2;  // output rows y0, y0+1
  const int t = threadIdx.x;
  const int wv = t >> 6, lane = t & 63, lm = lane & 15, kg = lane >> 4;
  const int wm = (CO_TILE == 256) ? (wv & 3) : 0;
  const int wn = (CO_TILE == 256) ? (wv >> 2) : (wv & 1);   // output row
  const int ph = (CO_TILE == 256) ? 0 : (wv >> 1);          // px half (32co)

  const ushort* inb = in + (size_t)b * (PLANE * 256);

  const int pxl = lane >> 5, gd = lane & 31;
  auto stage = [&](int ir, int bufi) {
#pragma unroll
    for (int n = 0; n < IPW; ++n) {
      int i = wv * IPW + n;
      int px = i * 2 + pxl;
      int gs = gd ^ (px & 7);
      gload_lds16(inb + ((size_t)(ir * 64 + px)) * 256 + gs * 8,
                  (char*)Bs[bufi] + i * 1024);
    }
  };

  f32x4 acc[MFR][NFR] = {};
  const ushort* wrow[MFR];
#pragma unroll
  for (int mi = 0; mi < MFR; ++mi) {
    int cor = wm * 64 + mi * 16 + lm;
    if (cor > Cout - 1) cor = Cout - 1;  // clamped rows land in D rows >= Cout
    wrow[mi] = wg + (size_t)cor * 256 + kg * 8;
  }
  const int wks = Cout * 256;

  auto compute = [&](int s) {
    const int ky = s - wn;
    const int ir = y0 + s - 1;
    if (ky < 0 || ky > 2 || (unsigned)ir >= 64u) return;
    const char* buf = (const char*)Bs[s & 1];
#pragma unroll
    for (int kx = 0; kx < 3; ++kx) {
      const int kk = ky * 3 + kx;
      int sb[NFR], swz[NFR];
      bool bval[NFR];
#pragma unroll
      for (int ni = 0; ni < NFR; ++ni) {
        int px = ph * 32 + ni * 16 + lm;
        int ix = px + kx - 1;
        bval[ni] = (unsigned)ix < 64u;
        int ixc = min(max(ix, 0), 63);
        sb[ni] = ixc * 512;
        swz[ni] = ixc & 7;
      }
#pragma unroll
      for (int cc = 0; cc < 4; ++cc) {
        bf16x8 af[MFR][2];
#pragma unroll
        for (int mi = 0; mi < MFR; ++mi)
#pragma unroll
          for (int ks = 0; ks < 2; ++ks)
            af[mi][ks] = *(const bf16x8*)(wrow[mi] + kk * wks + cc * 64 + ks * 32);
        bf16x8 z = {};
#pragma unroll
        for (int ni = 0; ni < NFR; ++ni) {
          bf16x8 bf[2];
#pragma unroll
          for (int ks = 0; ks < 2; ++ks) {
            int g = (cc * 8 + ks * 4 + kg) ^ swz[ni];
            bf16x8 v = *(const bf16x8*)(buf + sb[ni] + g * 16);
            bf[ks] = bval[ni] ? v : z;
          }
          __builtin_amdgcn_s_setprio(1);
#pragma unroll
          for (int mi = 0; mi < MFR; ++mi)
#pragma unroll
            for (int ks = 0; ks < 2; ++ks)
              acc[mi][ni] = __builtin_amdgcn_mfma_f32_16x16x32_bf16(
                  af[mi][ks], bf[ks], acc[mi][ni], 0, 0, 0);
          __builtin_amdgcn_s_setprio(0);
        }
      }
    }
  };

  // pipeline: step s computes input row y0+s-1 from buf s&1
  if (y0 - 1 >= 0) stage(y0 - 1, 0);
  asm volatile("s_waitcnt vmcnt(0)" ::: "memory");
  __syncthreads();
#pragma unroll
  for (int s = 0; s < 4; ++s) {
    if (s < 3) {
      int irn = y0 + s;
      if (irn <= 63) stage(irn, (s + 1) & 1);
    }
    compute(s);
    asm volatile("s_waitcnt vmcnt(0)" ::: "memory");
    __syncthreads();
  }

  // ---- epilogue ----
  const int yo = y0 + wn;
  if (OUT_BF16) {
    ushort* outb = (ushort*)outp + (size_t)b * (PLANE * 256) + (size_t)yo * 64 * 256;
#pragma unroll
    for (int mi = 0; mi < MFR; ++mi)
#pragma unroll
      for (int ni = 0; ni < NFR; ++ni) {
        int px = ph * 32 + ni * 16 + lm;
        int co0 = wm * 64 + mi * 16 + kg * 4;
        ushort4 h;
        h.x = f2bf(acc[mi][ni][0]); h.y = f2bf(acc[mi][ni][1]);
        h.z = f2bf(acc[mi][ni][2]); h.w = f2bf(acc[mi][ni][3]);
        *(ushort4*)(outb + (size_t)px * 256 + co0) = h;
      }
  } else {
    float* o = (float*)outp;
#pragma unroll
    for (int mi = 0; mi < MFR; ++mi)
#pragma unroll
      for (int ni = 0; ni < NFR; ++ni) {
        int px = ph * 32 + ni * 16 + lm;
#pragma unroll
        for (int rr = 0; rr < 4; ++rr) {
          int co = wm * 64 + mi * 16 + kg * 4 + rr;
          if (co < Cout)
            o[((size_t)(b * Cout + co)) * PLANE + yo * 64 + px] = acc[mi][ni][rr];
        }
      }
  }
}

// ---------------------------------------------------------------------------
// Tap-pipelined deformable conv3x3 (v1), PAIRED (grid 512, sub = bid>>8).
// Unchanged from round 9 (known-good 170 us paired).
// ---------------------------------------------------------------------------
__global__ __launch_bounds__(512, 2) void conv_dfm(
    const ushort* __restrict__ in0, const ushort* __restrict__ in1,
    const ushort* __restrict__ w0, const ushort* __restrict__ w1,
    ushort* __restrict__ o0, ushort* __restrict__ o1,
    const int4* __restrict__ idx4, const float4* __restrict__ wt4) {
  __shared__ __align__(16) ushort Ds[2][16384];

  const int sub = blockIdx.x >> 8;
  const ushort* in = sub ? in1 : in0;
  const ushort* wg = sub ? w1 : w0;
  ushort* outp = sub ? o1 : o0;

  const int bid = blockIdx.x & 255;
  const int r8 = bid & 7;
  const int b = r8 >> 1;
  const int y = (r8 & 1) * 32 + (bid >> 3);
  const int t = threadIdx.x;
  const int wv = t >> 6, lane = t & 63, lm = lane & 15, kg = lane >> 4;
  const int wm = wv & 3, wn = wv >> 2;
  const int spx = t >> 3, gd = t & 7;

  const ushort* inb = in + (size_t)b * (PLANE * 256);

  int4 tA; float4 wA;
  auto ldtbl = [&](int kk) {
    int pi = ((b * 9 + kk) * 64 + y) * 64 + spx;
    tA = idx4[pi]; wA = wt4[pi];
  };

  bf16x8 g[8];
  auto gather = [&](int ccp) {
#pragma unroll
    for (int q = 0; q < 2; ++q) {
      int cc = ccp * 2 + q;
      const ushort* cb = inb + (cc * 8 + gd) * 8;
      g[q * 4 + 0] = *(const bf16x8*)(cb + (size_t)tA.x * 256);
      g[q * 4 + 1] = *(const bf16x8*)(cb + (size_t)tA.y * 256);
      g[q * 4 + 2] = *(const bf16x8*)(cb + (size_t)tA.z * 256);
      g[q * 4 + 3] = *(const bf16x8*)(cb + (size_t)tA.w * 256);
    }
  };
  auto blend = [&](int ccp, int nb) {
#pragma unroll
    for (int q = 0; q < 2; ++q) {
      int cc = ccp * 2 + q;
      uint4 pk; ushort* hp = (ushort*)&pk;
#pragma unroll
      for (int j = 0; j < 8; ++j) {
        float f = wA.x * bf2f(((ushort*)&g[q * 4 + 0])[j])
                + wA.y * bf2f(((ushort*)&g[q * 4 + 1])[j])
                + wA.z * bf2f(((ushort*)&g[q * 4 + 2])[j])
                + wA.w * bf2f(((ushort*)&g[q * 4 + 3])[j]);
        hp[j] = f2bf(f);
      }
      int slot = (cc * 8 + gd) ^ (spx & 7);
      *(uint4*)((char*)Ds[nb] + spx * 512 + slot * 16) = pk;
    }
  };

  f32x4 acc[4][2] = {};
  const ushort* wrow[4];
#pragma unroll
  for (int mi = 0; mi < 4; ++mi)
    wrow[mi] = wg + (size_t)(wm * 64 + mi * 16 + lm) * 256 + kg * 8;

  int pxn[2], swz[2];
#pragma unroll
  for (int ni = 0; ni < 2; ++ni) {
    pxn[ni] = (wn * 32 + ni * 16 + lm) * 512;
    swz[ni] = (wn * 32 + ni * 16 + lm) & 7;
  }

  auto compute_cc = [&](int kk, int cur, int cc) {
    bf16x8 af[4][2], bf[2][2];
#pragma unroll
    for (int mi = 0; mi < 4; ++mi)
#pragma unroll
      for (int ks = 0; ks < 2; ++ks)
        af[mi][ks] = *(const bf16x8*)(wrow[mi] + kk * 65536 + cc * 64 + ks * 32);
#pragma unroll
    for (int ni = 0; ni < 2; ++ni)
#pragma unroll
      for (int ks = 0; ks < 2; ++ks) {
        int gs = (cc * 8 + ks * 4 + kg) ^ swz[ni];
        bf[ni][ks] = *(const bf16x8*)((const char*)Ds[cur] + pxn[ni] + gs * 16);
      }
    __builtin_amdgcn_s_setprio(1);
#pragma unroll
    for (int mi = 0; mi < 4; ++mi)
#pragma unroll
      for (int ni = 0; ni < 2; ++ni)
#pragma unroll
        for (int ks = 0; ks < 2; ++ks)
          acc[mi][ni] = __builtin_amdgcn_mfma_f32_16x16x32_bf16(
              af[mi][ks], bf[ni][ks], acc[mi][ni], 0, 0, 0);
    __builtin_amdgcn_s_setprio(0);
  };

  ldtbl(0);
  gather(0); blend(0, 0);
  gather(1); blend(1, 0);
  ldtbl(1);
  __syncthreads();

  for (int kk = 0; kk < 9; ++kk) {
    const int cur = kk & 1, nb = cur ^ 1;
    const bool pf = (kk < 8);
    if (pf) gather(0);
    compute_cc(kk, cur, 0);
    compute_cc(kk, cur, 1);
    if (pf) { blend(0, nb); gather(1); }
    compute_cc(kk, cur, 2);
    compute_cc(kk, cur, 3);
    if (pf) {
      blend(1, nb);
      if (kk + 2 < 9) ldtbl(kk + 2);
    }
    __syncthreads();
  }

  ushort* outb = outp + (size_t)b * (PLANE * 256) + (size_t)y * 64 * 256;
#pragma unroll
  for (int mi = 0; mi < 4; ++mi)
#pragma unroll
    for (int ni = 0; ni < 2; ++ni) {
      int px = wn * 32 + ni * 16 + lm;
      int co0 = wm * 64 + mi * 16 + kg * 4;
      ushort4 h;
      h.x = f2bf(acc[mi][ni][0]); h.y = f2bf(acc[mi][ni][1]);
      h.z = f2bf(acc[mi][ni][2]); h.w = f2bf(acc[mi][ni][3]);
      *(ushort4*)(outb + (size_t)px * 256 + co0) = h;
    }
}

// ---------------------------------------------------------------------------
__global__ __launch_bounds__(256) void tr_nhwc(const float* __restrict__ src,
                                               ushort* __restrict__ dst) {
  __shared__ ushort T[64][264];
  int y = blockIdx.x, b = blockIdx.y, t = threadIdx.x;
  const float* s = src + (size_t)b * 1048576 + y * 64;
  int ci0 = t >> 2, f4 = t & 3;
#pragma unroll
  for (int cb = 0; cb < 4; ++cb) {
    int ci = cb * 64 + ci0;
#pragma unroll
    for (int l = 0; l < 4; ++l) {
      int px = (f4 + l * 4) * 4;
      float4 v = *(const float4*)(s + (size_t)ci * 4096 + px);
      T[px + 0][ci] = f2bf(v.x);
      T[px + 1][ci] = f2bf(v.y);
      T[px + 2][ci] = f2bf(v.z);
      T[px + 3][ci] = f2bf(v.w);
    }
  }
  __syncthreads();
  ushort* d = dst + (size_t)(b * 4096 + y * 64) * 256;
#pragma unroll
  for (int k = 0; k < 8; ++k) {
    int u = t + k * 256;
    int px = u >> 5, c32 = u & 31;
    uint4 vv = *(const uint4*)&T[px][c32 * 8];
    *(uint4*)(d + (size_t)px * 256 + c32 * 8) = vv;
  }
}

// ---------------------------------------------------------------------------
__global__ __launch_bounds__(256) void precomp_offsets(
    const float* __restrict__ off, int4* __restrict__ idx4,
    float4* __restrict__ wt4) {
  int tid = blockIdx.x * 256 + threadIdx.x;
  if (tid >= 4 * 9 * PLANE) return;
  int x = tid & 63, y = (tid >> 6) & 63;
  int kk = (tid >> 12) % 9;
  int b = tid / (9 * PLANE);
  float dy = off[((b * 18 + 2 * kk) * 64 + y) * 64 + x];
  float dx = off[((b * 18 + 2 * kk + 1) * 64 + y) * 64 + x];
  float sy = dy + (float)(y - 1 + kk / 3);
  float sx = dx + (float)(x - 1 + kk % 3);
  float y0f = floorf(sy), x0f = floorf(sx);
  float wy = sy - y0f, wx = sx - x0f;
  int y0 = (int)y0f, x0 = (int)x0f, y1 = y0 + 1, x1 = x0 + 1;
  float vy0 = ((unsigned)y0 < 64u) ? 1.f : 0.f;
  float vy1 = ((unsigned)y1 < 64u) ? 1.f : 0.f;
  float vx0 = ((unsigned)x0 < 64u) ? 1.f : 0.f;
  float vx1 = ((unsigned)x1 < 64u) ? 1.f : 0.f;
  int cy0 = min(max(y0, 0), 63), cy1 = min(max(y1, 0), 63);
  int cx0 = min(max(x0, 0), 63), cx1 = min(max(x1, 0), 63);
  idx4[tid] = make_int4(cy0 * 64 + cx0, cy0 * 64 + cx1,
                        cy1 * 64 + cx0, cy1 * 64 + cx1);
  wt4[tid] = make_float4((1.f - wy) * (1.f - wx) * vy0 * vx0,
                         (1.f - wy) * wx * vy0 * vx1,
                         wy * (1.f - wx) * vy1 * vx0, wy * wx * vy1 * vx1);
}

// ---------------------------------------------------------------------------
__global__ __launch_bounds__(256) void gn_stats(const ushort* __restrict__ x0,
                                                const ushort* __restrict__ x1,
                                                float2* __restrict__ stats) {
  int bgg = blockIdx.x;
  int sub = bgg >> 7, bg = bgg & 127;
  const ushort* x = sub ? x1 : x0;
  int b = bg >> 5, g = bg & 31;
  const uint4* base = (const uint4*)(x + (size_t)b * 1048576 + g * 8);
  float s = 0.f, q = 0.f;
#pragma unroll
  for (int k = 0; k < 16; ++k) {
    int p = threadIdx.x + k * 256;
    uint4 v = base[(size_t)p * 32];
    const ushort* h = (const ushort*)&v;
#pragma unroll
    for (int j = 0; j < 8; ++j) { float f = bf2f(h[j]); s += f; q += f * f; }
  }
#pragma unroll
  for (int o = 32; o; o >>= 1) { s += __shfl_xor(s, o); q += __shfl_xor(q, o); }
  __shared__ float ss[4], qq[4];
  int wid = threadIdx.x >> 6;
  if ((threadIdx.x & 63) == 0) { ss[wid] = s; qq[wid] = q; }
  __syncthreads();
  if (threadIdx.x == 0) {
    s = ss[0] + ss[1] + ss[2] + ss[3];
    q = qq[0] + qq[1] + qq[2] + qq[3];
    float m = s / 32768.f;
    float v = q / 32768.f - m * m;
    stats[bgg] = make_float2(m, rsqrtf(v + 1e-5f));
  }
}

__global__ __launch_bounds__(256) void gn_apply(
    const ushort* __restrict__ x0, const ushort* __restrict__ x1,
    const float2* __restrict__ stats,
    const float* __restrict__ ga0, const float* __restrict__ be0,
    const float* __restrict__ ga1, const float* __restrict__ be1,
    ushort* __restrict__ o0, ushort* __restrict__ o1) {
  int i = blockIdx.x * 256 + threadIdx.x;
  int sub = i >> 19, il = i & 524287;
  const ushort* x = sub ? x1 : x0;
  const float* gamma = sub ? ga1 : ga0;
  const float* beta = sub ? be1 : be0;
  ushort* out = sub ? o1 : o0;
  uint4 v = ((const uint4*)x)[il];
  int cg = il & 31;
  int b = il >> 17;
  float2 st = stats[sub * 128 + b * 32 + cg];
  const float4* gp = (const float4*)(gamma + cg * 8);
  const float4* bp = (const float4*)(beta + cg * 8);
  float4 g0 = gp[0], g1 = gp[1], b0 = bp[0], b1 = bp[1];
  float ga[8] = {g0.x, g0.y, g0.z, g0.w, g1.x, g1.y, g1.z, g1.w};
  float bb[8] = {b0.x, b0.y, b0.z, b0.w, b1.x, b1.y, b1.z, b1.w};
  ushort* h = (ushort*)&v;
#pragma unroll
  for (int j = 0; j < 8; ++j) {
    float a = st.y * ga[j];
    h[j] = f2bf(bf2f(h[j]) * a + (bb[j] - st.x * a));
  }
  ((uint4*)out)[il] = v;
}

// ---------------------------------------------------------------------------
struct WJobs {
  const float* src[12];
  ushort* dst[12];
  int cout[12];
};
__global__ __launch_bounds__(256) void wcvt(WJobs j) {
  int job = blockIdx.z, kk = blockIdx.y, co = blockIdx.x, ci = threadIdx.x;
  int Cout = j.cout[job];
  if (co >= Cout) return;
  j.dst[job][((size_t)kk * Cout + co) * 256 + ci] =
      f2bf(j.src[job][co * 2304 + ci * 9 + kk]);
}

// ---------------------------------------------------------------------------
__global__ __launch_bounds__(256) void rp_out(const float* __restrict__ off1,
                                              const float* __restrict__ off2,
                                              float* __restrict__ out) {
  int tid = blockIdx.x * 256 + threadIdx.x;
  if (tid >= OFF_ELEMS) return;
  int x = tid & 63, y = (tid >> 6) & 63;
  int ch = (tid >> 12) % 18;
  int k = ch >> 1;
  float base = (ch & 1) ? (float)(x + (k % 3) - 1) : (float)(y + (k / 3) - 1);
  float r1 = base + off1[tid];
  out[tid] = r1;
  out[OFF_ELEMS + tid] = r1 + off2[tid];
}

// ---------------------------------------------------------------------------
extern "C" void kernel_launch(void* const* d_in, const int* in_sizes, int n_in,
                              void* d_out, int out_size, void* d_ws,
                              size_t ws_size, hipStream_t stream) {
  (void)in_sizes; (void)n_in; (void)out_size; (void)ws_size;
  const float* feature = (const float*)d_in[0];
  const float* loc_ws  = (const float*)d_in[1];
  const float* loc_g   = (const float*)d_in[2];
  const float* loc_b   = (const float*)d_in[3];
  const float* cls_ws  = (const float*)d_in[4];
  const float* cls_g   = (const float*)d_in[5];
  const float* cls_b   = (const float*)d_in[6];
  const float* pi_w    = (const float*)d_in[7];
  const float* pio_w   = (const float*)d_in[8];
  const float* prd_w   = (const float*)d_in[9];
  const float* pro_w   = (const float*)d_in[10];
  const float* cd_w    = (const float*)d_in[11];
  const float* co_w    = (const float*)d_in[12];
  float* out = (float*)d_out;

  char* p = (char*)d_ws;
  int4*   idx4 = (int4*)p;            p += 147456 * 16;
  float4* wt4  = (float4*)p;          p += 147456 * 16;
  ushort* feat_bf = (ushort*)p;       p += 4194304 * 2;
  ushort* wg      = (ushort*)p;       p += 9 * 589824 * 2;
  ushort* wgpio   = (ushort*)p;       p += 41472 * 2;
  ushort* wgpro   = (ushort*)p;       p += 41472 * 2;
  ushort* wgco    = (ushort*)p;       p += 34560 * 2;
  ushort* aL      = (ushort*)p;       p += 4194304 * 2;
  ushort* bL      = (ushort*)p;       p += 4194304 * 2;
  ushort* aC      = (ushort*)p;       p += 4194304 * 2;
  ushort* bC      = (ushort*)p;       p += 4194304 * 2;
  float*  off1    = (float*)p;        p += OFF_ELEMS * 4;
  float*  off2    = (float*)p;        p += OFF_ELEMS * 4;
  float2* stats   = (float2*)p;       p += 256 * 8;

  ushort* WG[9];
  for (int i = 0; i < 9; ++i) WG[i] = wg + (size_t)i * 589824;

  dim3 blk(256);
  tr_nhwc<<<dim3(64, 4), blk, 0, stream>>>(feature, feat_bf);
  WJobs jobs;
  const float* srcs[12] = {loc_ws, loc_ws + 589824, loc_ws + 2 * 589824,
                           cls_ws, cls_ws + 589824, cls_ws + 2 * 589824,
                           pi_w,   prd_w,           cd_w,
                           pio_w,  pro_w,           co_w};
  ushort* dsts[12] = {WG[0], WG[1], WG[2], WG[3], WG[4], WG[5],
                      WG[6], WG[7], WG[8], wgpio, wgpro, wgco};
  int couts[12] = {256,256,256,256,256,256,256,256,256,18,18,15};
  for (int i = 0; i < 12; ++i) {
    jobs.src[i] = srcs[i]; jobs.dst[i] = dsts[i]; jobs.cout[i] = couts[i];
  }
  wcvt<<<dim3(256, 9, 12), blk, 0, stream>>>(jobs);

  auto conv2 = [&](const ushort* i0, const ushort* w0, ushort* o0,
                   const ushort* i1, const ushort* w1, ushort* o1) {
    conv_std2<256, true><<<dim3(256), dim3(512), 0, stream>>>(
        i0, i1, w0, w1, o0, o1, 256, 256);
  };
  auto conv1 = [&](const ushort* i0, const ushort* w0, ushort* o0) {
    conv_std2<256, true><<<dim3(128), dim3(512), 0, stream>>>(
        i0, i0, w0, w0, o0, o0, 256, 256);
  };
  auto dconv2 = [&](const ushort* i0, const ushort* w0, ushort* o0,
                    const ushort* i1, const ushort* w1, ushort* o1) {
    conv_dfm<<<dim3(512), dim3(512), 0, stream>>>(i0, i1, w0, w1, o0, o1,
                                                  idx4, wt4);
  };
  auto sconv2 = [&](const ushort* i0, const ushort* w0, float* o0, int c0,
                    const ushort* i1, const ushort* w1, float* o1, int c1) {
    conv_std2<32, false><<<dim3(256), dim3(256), 0, stream>>>(
        i0, i1, w0, w1, o0, o1, c0, c1);
  };
  auto sconv1 = [&](const ushort* i0, const ushort* w0, float* o0, int c0) {
    conv_std2<32, false><<<dim3(128), dim3(256), 0, stream>>>(
        i0, i0, w0, w0, o0, o0, c0, c0);
  };
  auto gn2 = [&](const ushort* x0, const float* g0, const float* e0, ushort* o0,
                 const ushort* x1, const float* g1, const float* e1, ushort* o1) {
    gn_stats<<<dim3(256), blk, 0, stream>>>(x0, x1, stats);
    gn_apply<<<dim3(4096), blk, 0, stream>>>(x0, x1, stats, g0, e0, g1, e1,
                                             o0, o1);
  };

  // ---- trunk: loc & cls paired ----
  conv2(feat_bf, WG[0], aL, feat_bf, WG[3], aC);
  gn2(aL, loc_g + 0, loc_b + 0, bL, aC, cls_g + 0, cls_b + 0, bC);
  conv2(bL, WG[1], aL, bC, WG[4], aC);
  gn2(aL, loc_g + 256, loc_b + 256, bL, aC, cls_g + 256, cls_b + 256, bC);
  conv2(bL, WG[2], aL, bC, WG[5], aC);
  gn2(aL, loc_g + 512, loc_b + 512, bL, aC, cls_g + 512, cls_b + 512, bC);
  // bL = loc, bC = clsf

  // ---- offset head (loc-only) ----
  conv1(bL, WG[6], aL);                            // pi
  sconv1(aL, wgpio, off1, 18);                     // offset1 (fp32 NCHW)
  precomp_offsets<<<dim3(576), blk, 0, stream>>>(off1, idx4, wt4);

  // ---- paired deform + paired small convs ----
  dconv2(bL, WG[7], aL, bC, WG[8], aC);            // deform(loc) | deform(clsf)
  sconv2(aL, wgpro, off2, 18, aC, wgco, out + CLS_OFF, 15);

  // ---- rep points ----
  rp_out<<<dim3(1152), blk, 0, stream>>>(off1, off2, out);
}